// Round 17
// baseline (294.806 us; speedup 1.0000x reference)
//
#include <hip/hip_runtime.h>

#define NEGF (-1e30f)
#define LOG2E 1.4426950408889634f
#define LN2d  0.6931471805599453

typedef __attribute__((ext_vector_type(8))) short bf16x8;
typedef __attribute__((ext_vector_type(4))) float f32x4;

__device__ __forceinline__ unsigned short f2bf(float x) {
  unsigned u = __float_as_uint(x);
  unsigned r = (u + 0x7FFFu + ((u >> 16) & 1u)) >> 16;
  return (unsigned short)r;
}

// ===========================================================================
// Device bodies
// ===========================================================================

__device__ __forceinline__ void d_cvtx(int bid, int tid,
                                       const float* __restrict__ X,
                                       unsigned short* __restrict__ Xbf) {
  const int i = bid * 256 + tid;
  float4 v = ((const float4*)X)[i];
  ushort4 h;
  h.x = f2bf(v.x); h.y = f2bf(v.y); h.z = f2bf(v.z); h.w = f2bf(v.w);
  ((ushort4*)Xbf)[i] = h;
}

__device__ __forceinline__ void d_gather(int bid, int tid,
                                         const float* __restrict__ W,
                                         const float* __restrict__ b,
                                         const int* __restrict__ labels,
                                         float* __restrict__ Wgt,
                                         float* __restrict__ gb) {
  const int n  = bid >> 7;
  const int kc = bid & 127;
  const int k0 = kc << 2;
  for (int idx = tid; idx < 4 * 129; idx += 256) {
    const int kk = idx / 129;
    const int j  = idx - kk * 129;
    const int c  = (j == 0) ? 0 : labels[n * 128 + (j - 1)];
    const int k  = k0 + kk;
    Wgt[((size_t)(n * 512 + k)) * 132 + j] = W[(size_t)k * 4096 + c];
    if (kc == 0 && kk == 0) gb[n * 129 + j] = b[c];
  }
}

__device__ __forceinline__ void d_wtrans(int bid, int tid, char* smem,
                                         const float* __restrict__ W,
                                         unsigned short* __restrict__ Wt) {
  float (*tile)[65] = (float (*)[65])smem;
  const int kb = bid & 7;
  const int vb = bid >> 3;
  const int k0 = kb << 6, v0 = vb << 6;
#pragma unroll
  for (int it = 0; it < 16; ++it) {
    const int idx = it * 256 + tid;
    const int r = idx >> 6, c = idx & 63;
    tile[r][c] = W[(size_t)(k0 + r) * 4096 + v0 + c];
  }
  __syncthreads();
#pragma unroll
  for (int it = 0; it < 16; ++it) {
    const int idx = it * 256 + tid;
    const int vr = idx >> 6, kc = idx & 63;
    Wt[(size_t)(v0 + vr) * 512 + k0 + kc] = f2bf(tile[kc][vr]);
  }
}

// ---- glp8 producer body: 8 rows/block, log2-domain raw logits, then flag --
__device__ void d_glp8(int idx, int tid, char* smem,
                       const float* __restrict__ X,
                       const float* __restrict__ Wgt,
                       const float* __restrict__ gb,
                       const int* __restrict__ lens,
                       float* __restrict__ g,
                       int* __restrict__ cnt) {
  const int n  = idx >> 6;
  const int r0 = (idx & 63) << 3;
  const int fc = n * 16 + (r0 >> 5);     // flag slot for this 32-row chunk
  if (r0 >= lens[n]) {                   // no data needed: signal only
    if (tid == 0) atomicAdd(&cnt[fc], 1);
    return;
  }
  const int m0 = n * 512 + r0;
  float (*xs)[512] = (float (*)[512])smem;   // 16 KB
  {
    const float4* Xv = (const float4*)(X + (size_t)m0 * 512);
    float4* xsv = (float4*)(&xs[0][0]);
    for (int i = tid; i < 8 * 128; i += 256) xsv[i] = Xv[i];
  }
  __syncthreads();
  const int j = tid;
  if (j < 129) {
    const float* wp = Wgt + (size_t)(n * 512) * 132 + j;
    float acc[8];
#pragma unroll
    for (int r = 0; r < 8; ++r) acc[r] = 0.f;
    float w0 = wp[0], w1 = wp[132], w2 = wp[264], w3 = wp[396];
    for (int k4 = 0; k4 < 128; ++k4) {
      const int kn = (k4 + 1) & 127;
      float p0 = wp[(size_t)(kn * 4 + 0) * 132];
      float p1 = wp[(size_t)(kn * 4 + 1) * 132];
      float p2 = wp[(size_t)(kn * 4 + 2) * 132];
      float p3 = wp[(size_t)(kn * 4 + 3) * 132];
#pragma unroll
      for (int r = 0; r < 8; ++r) {
        float4 x4 = *(const float4*)(&xs[r][k4 << 2]);
        acc[r] = fmaf(x4.x, w0, acc[r]);
        acc[r] = fmaf(x4.y, w1, acc[r]);
        acc[r] = fmaf(x4.z, w2, acc[r]);
        acc[r] = fmaf(x4.w, w3, acc[r]);
      }
      w0 = p0; w1 = p1; w2 = p2; w3 = p3;
    }
    const float bb = gb[n * 129 + j];
#pragma unroll
    for (int r = 0; r < 8; ++r)
      g[(size_t)(m0 + r) * 132 + j] = (acc[r] + bb) * LOG2E;
  }
  __threadfence();                       // per-thread writes device-visible
  __syncthreads();                       // all threads fenced
  if (tid == 0) atomicAdd(&cnt[fc], 1);
}

// ---- gemm body (bf16 MFMA, swizzled, validated r12) ----------------------
__device__ __forceinline__ void stage_tile(const unsigned short* __restrict__ src,
                                           int r0, char* ldsbase, int wave,
                                           int tid, int kbyte) {
#pragma unroll
  for (int j = 0; j < 2; ++j) {
    const int chunk = (tid & 3) ^ ((tid >> 3) & 3);
    const char* gp = (const char*)src +
        (size_t)(r0 + j * 64 + (tid >> 2)) * 1024 + kbyte + chunk * 16;
    char* lp = ldsbase + j * 4096 + wave * 1024;
    __builtin_amdgcn_global_load_lds(
        (const __attribute__((address_space(1))) unsigned int*)gp,
        (__attribute__((address_space(3))) unsigned int*)lp, 16, 0, 0);
  }
}

__device__ __forceinline__ void d_gemm(int gid, int tid, char* smem,
                                       const unsigned short* __restrict__ Xbf,
                                       const unsigned short* __restrict__ Wt,
                                       const float* __restrict__ bvec,
                                       const int* __restrict__ lens,
                                       float* __restrict__ pg) {
  const int bm = gid >> 5;
  const int bn = gid & 31;
  const int n  = bm >> 2;
  const int t0 = (bm & 3) << 7;
  if (t0 >= lens[n]) return;
  const int m0 = bm << 7;
  const int v0 = bn << 7;

  const int wave = tid >> 6;
  const int lane = tid & 63;
  const int lrow = lane & 15;
  const int lk   = (lane >> 4) * 16;
  const int lks  = lk ^ (((lrow >> 1) & 3) << 4);
  const int wr   = wave >> 1;
  const int wn   = wave & 1;

  f32x4 acc[4][4];
#pragma unroll
  for (int mi = 0; mi < 4; ++mi)
#pragma unroll
    for (int ni = 0; ni < 4; ++ni) acc[mi][ni] = (f32x4){0.f, 0.f, 0.f, 0.f};

  {
    char* buf = smem;
    stage_tile(Xbf, m0, buf + 0,    wave, tid, 0);
    stage_tile(Wt,  v0, buf + 8192, wave, tid, 0);
  }
  __syncthreads();

  int cur = 0;
  for (int kk = 0; kk < 16; ++kk) {
    if (kk < 15) {
      char* nbuf = smem + (cur ^ 1) * 16384;
      const int kb = (kk + 1) << 6;
      stage_tile(Xbf, m0, nbuf + 0,    wave, tid, kb);
      stage_tile(Wt,  v0, nbuf + 8192, wave, tid, kb);
    }
    const char* buf = smem + cur * 16384;
    bf16x8 ah[4], bh[4];
#pragma unroll
    for (int mi = 0; mi < 4; ++mi) {
      const int off = (wr * 64 + mi * 16 + lrow) * 64 + lks;
      ah[mi] = *(const bf16x8*)(buf + off);
    }
#pragma unroll
    for (int ni = 0; ni < 4; ++ni) {
      const int off = (wn * 64 + ni * 16 + lrow) * 64 + lks;
      bh[ni] = *(const bf16x8*)(buf + 8192 + off);
    }
#pragma unroll
    for (int mi = 0; mi < 4; ++mi)
#pragma unroll
      for (int ni = 0; ni < 4; ++ni)
        acc[mi][ni] = __builtin_amdgcn_mfma_f32_16x16x32_bf16(ah[mi], bh[ni], acc[mi][ni], 0, 0, 0);
    __syncthreads();
    cur ^= 1;
  }

  const float lg2e = LOG2E;
  float bias[4];
#pragma unroll
  for (int ni = 0; ni < 4; ++ni) bias[ni] = bvec[v0 + wn * 64 + ni * 16 + lrow];
  float* part = (float*)(smem + 32768);
#pragma unroll
  for (int mi = 0; mi < 4; ++mi)
#pragma unroll
    for (int reg = 0; reg < 4; ++reg) {
      float s = 0.f;
#pragma unroll
      for (int ni = 0; ni < 4; ++ni)
        s += exp2f((acc[mi][ni][reg] + bias[ni]) * lg2e);
#pragma unroll
      for (int msk = 1; msk < 16; msk <<= 1) s += __shfl_xor(s, msk);
      if (lrow == 0)
        part[(wr * 64 + mi * 16 + (lane >> 4) * 4 + reg) * 2 + wn] = s;
    }
  __syncthreads();
  if (tid < 128)
    pg[(size_t)(m0 + tid) * 32 + bn] = part[tid * 2 + 0] + part[tid * 2 + 1];
}

// ---- CTC scan body (fwd/bwd split, LOG2 domain) + chunk flag waits -------
__device__ __forceinline__ float lae32(float x, float y, float z) {
  float m = fmaxf(fmaxf(x, y), z);
  float e = exp2f(x - m) + exp2f(y - m) + exp2f(z - m);
  return m + __log2f(e);
}

__device__ __forceinline__ float lae3n(float x, float y, float z) {
  float m = fmaxf(fmaxf(x, y), z);
  float e = __expf(x - m) + __expf(y - m) + __expf(z - m);
  return m + __logf(e);
}

__device__ __forceinline__ void stage32(const float* __restrict__ gsrc,
                                        char* ldsbase, int tid, int wave) {
#pragma unroll
  for (int k = 0; k < 4; ++k) {
    const char* gp = (const char*)gsrc + k * 4096 + (size_t)tid * 16;
    char* lp = ldsbase + k * 4096 + wave * 1024;
    __builtin_amdgcn_global_load_lds(
        (const __attribute__((address_space(1))) unsigned int*)gp,
        (__attribute__((address_space(3))) unsigned int*)lp, 16, 0, 0);
  }
  if (tid < 32) {
    const char* gp = (const char*)gsrc + 16384 + (size_t)tid * 16;
    char* lp = ldsbase + 16384;
    __builtin_amdgcn_global_load_lds(
        (const __attribute__((address_space(1))) unsigned int*)gp,
        (__attribute__((address_space(3))) unsigned int*)lp, 16, 0, 0);
  }
}

__device__ __forceinline__ void waitchunk(int* cnt, int slot, int tid) {
  if (tid == 0) {
    while (atomicAdd(&cnt[slot], 0) < 4) { __builtin_amdgcn_s_sleep(8); }
  }
  __syncthreads();
}

__device__ void d_scan(int sbid, int tid, char* smem,
                       const float* __restrict__ g,
                       const int* __restrict__ labels,
                       const int* __restrict__ in_lens,
                       const int* __restrict__ lab_lens,
                       float* __restrict__ af,
                       float* __restrict__ ab,
                       int* __restrict__ cnt) {
  const int n    = sbid >> 1;
  const int dir  = sbid & 1;
  const int wave = tid >> 6;
  const int l    = tid & 63;
  const int len  = in_lens[n];
  const int tm   = len >> 1;
  const float* gn = g + (size_t)n * 512 * 132;
  const int s0 = 5 * l;

  int jm0, jm1, jm2, jm3, jm4;
  {
    int jmv[5];
#pragma unroll
    for (int i = 0; i < 5; ++i) {
      const int s = s0 + i;
      jmv[i] = (s < 257 && (s & 1)) ? ((s + 1) >> 1) : 0;
    }
    jm0 = jmv[0]; jm1 = jmv[1]; jm2 = jmv[2]; jm3 = jmv[3]; jm4 = jmv[4];
  }

  if (dir == 0) {
    bool sk0, sk1, sk2, sk3, sk4;
    {
      bool skv[5];
#pragma unroll
      for (int i = 0; i < 5; ++i) {
        const int s = s0 + i;
        skv[i] = false;
        if (s < 257 && (s & 1) && s >= 3) {
          const int li = (s - 1) >> 1;
          const int cl = labels[n * 128 + li];
          skv[i] = (cl != 0) && (cl != labels[n * 128 + li - 1]);
        }
      }
      sk0 = skv[0]; sk1 = skv[1]; sk2 = skv[2]; sk3 = skv[3]; sk4 = skv[4];
    }
    waitchunk(cnt, n * 16, tid);
    stage32(gn, smem, tid, wave);
    __syncthreads();

    float a0 = NEGF, a1 = NEGF, a2 = NEGF, a3 = NEGF, a4 = NEGF;
    if (tid < 64 && l == 0) {
      const float* B0 = (const float*)smem;
      a0 = B0[0]; a1 = B0[1];
    }
    float a3p = NEGF, a4p = NEGF;

    int t = 1, c = 0;
    while (true) {
      const bool more = ((c + 1) << 5) <= tm;
      if (more) {
        waitchunk(cnt, n * 16 + c + 1, tid);
        stage32(gn + (size_t)((c + 1) << 5) * 132,
                smem + ((c + 1) & 1) * 16896, tid, wave);
      }
      if (tid < 64) {
        const float* B = (const float*)(smem + (c & 1) * 16896);
        const int ce = (c << 5) + 31;
        const int tend = (tm < ce) ? tm : ce;
        int ro = (t - (c << 5)) * 132;
        float p0 = B[ro + jm0], p1 = B[ro + jm1], p2 = B[ro + jm2],
              p3 = B[ro + jm3], p4 = B[ro + jm4];
        for (; t <= tend; ++t) {
          const int ro2 = (t < tend) ? ro + 132 : ro;
          const float q0 = B[ro2 + jm0];
          const float q1 = B[ro2 + jm1];
          const float q2 = B[ro2 + jm2];
          const float q3 = B[ro2 + jm3];
          const float q4 = B[ro2 + jm4];
          float x3 = a3p, x4 = a4p;
          if (l == 0) { x3 = NEGF; x4 = NEGF; }
          const float n3 = lae32(a3, a2, sk3 ? a1 : NEGF) + p3;
          const float n4 = lae32(a4, a3, sk4 ? a2 : NEGF) + p4;
          a3p = __shfl_up(n3, 1);
          a4p = __shfl_up(n4, 1);
          const float n0 = lae32(a0, x4, sk0 ? x3 : NEGF) + p0;
          const float n1 = lae32(a1, a0, sk1 ? x4 : NEGF) + p1;
          const float n2 = lae32(a2, a1, sk2 ? a0 : NEGF) + p2;
          a0 = n0; a1 = n1; a2 = n2; a3 = n3; a4 = n4;
          p0 = q0; p1 = q1; p2 = q2; p3 = q3; p4 = q4;
          ro = ro2;
        }
      }
      if (!more) break;
      __syncthreads();
      ++c;
    }
    if (tid < 64) {
      float* o = af + n * 320 + s0;
      o[0] = a0; o[1] = a1; o[2] = a2; o[3] = a3; o[4] = a4;
    }
  } else {
    bool skd0, skd1, skd2, skd3, skd4;
    {
      bool skv[5];
#pragma unroll
      for (int i = 0; i < 5; ++i) {
        const int s2 = s0 + i + 2;
        skv[i] = false;
        if (s2 < 257 && (s2 & 1) && s2 >= 3) {
          const int li = (s2 - 1) >> 1;
          const int cl = labels[n * 128 + li];
          skv[i] = (cl != 0) && (cl != labels[n * 128 + li - 1]);
        }
      }
      skd0 = skv[0]; skd1 = skv[1]; skd2 = skv[2]; skd3 = skv[3]; skd4 = skv[4];
    }
    int c = (len - 1) >> 5;
    waitchunk(cnt, n * 16 + c, tid);
    stage32(gn + (size_t)(c << 5) * 132, smem + (c & 1) * 16896, tid, wave);
    __syncthreads();

    float b0, b1, b2, b3, b4;
    {
      const int ll = lab_lens[n];
      const int i1 = 2 * ll, i2 = 2 * ll - 1;
      b0 = (s0 + 0 == i1 || s0 + 0 == i2) ? 0.f : NEGF;
      b1 = (s0 + 1 == i1 || s0 + 1 == i2) ? 0.f : NEGF;
      b2 = (s0 + 2 == i1 || s0 + 2 == i2) ? 0.f : NEGF;
      b3 = (s0 + 3 == i1 || s0 + 3 == i2) ? 0.f : NEGF;
      b4 = (s0 + 4 == i1 || s0 + 4 == i2) ? 0.f : NEGF;
    }

    int t = len - 2;
    while (true) {
      const bool more = (c << 5) > tm + 1;
      if (more) {
        waitchunk(cnt, n * 16 + c - 1, tid);
        stage32(gn + (size_t)((c - 1) << 5) * 132,
                smem + ((c - 1) & 1) * 16896, tid, wave);
      }
      if (tid < 64) {
        const float* B = (const float*)(smem + (c & 1) * 16896);
        const int cl0 = (c << 5) - 1;
        const int tlo = (tm > cl0) ? tm : cl0;
        int ro = (t + 1 - (c << 5)) * 132;
        float p0 = B[ro + jm0], p1 = B[ro + jm1], p2 = B[ro + jm2],
              p3 = B[ro + jm3], p4 = B[ro + jm4];
        for (; t >= tlo; --t) {
          const int ro2 = (t - 1 >= tlo) ? ro - 132 : ro;
          const float q0 = B[ro2 + jm0];
          const float q1 = B[ro2 + jm1];
          const float q2 = B[ro2 + jm2];
          const float q3 = B[ro2 + jm3];
          const float q4 = B[ro2 + jm4];
          const float c0 = b0 + p0;
          const float c1 = b1 + p1;
          float c5 = __shfl_down(c0, 1);
          float c6 = __shfl_down(c1, 1);
          const float c2 = b2 + p2;
          const float c3 = b3 + p3;
          const float c4 = b4 + p4;
          const float m0n = lae32(c0, c1, skd0 ? c2 : NEGF);
          const float m1n = lae32(c1, c2, skd1 ? c3 : NEGF);
          const float m2n = lae32(c2, c3, skd2 ? c4 : NEGF);
          if (l == 63) { c5 = NEGF; c6 = NEGF; }
          const float m3n = lae32(c3, c4, skd3 ? c5 : NEGF);
          const float m4n = lae32(c4, c5, skd4 ? c6 : NEGF);
          b0 = m0n; b1 = m1n; b2 = m2n; b3 = m3n; b4 = m4n;
          p0 = q0; p1 = q1; p2 = q2; p3 = q3; p4 = q4;
          ro = ro2;
        }
      }
      if (!more) break;
      __syncthreads();
      --c;
    }
    if (tid < 64) {
      float* o = ab + n * 320 + s0;
      o[0] = b0; o[1] = b1; o[2] = b2; o[3] = b3; o[4] = b4;
    }
  }
}

// ===========================================================================
// Launchers (main path)
// ===========================================================================

// prep1: [0,4096) cvtx ; [4096,6144) gather ; [6144,6656) wtrans ; 6656 cnt=0
__global__ __launch_bounds__(256) void k_prep1(const float* __restrict__ X,
                                               unsigned short* __restrict__ Xbf,
                                               const float* __restrict__ W,
                                               const float* __restrict__ b,
                                               const int* __restrict__ labels,
                                               float* __restrict__ Wgt,
                                               float* __restrict__ gb,
                                               unsigned short* __restrict__ Wt,
                                               int* __restrict__ cnt) {
  __shared__ __align__(16) char smem[16640];
  const int bid = blockIdx.x;
  if (bid < 4096)      d_cvtx(bid, threadIdx.x, X, Xbf);
  else if (bid < 6144) d_gather(bid - 4096, threadIdx.x, W, b, labels, Wgt, gb);
  else if (bid < 6656) d_wtrans(bid - 6144, threadIdx.x, smem, W, Wt);
  else                 cnt[threadIdx.x] = 0;   // 256 flag slots
}

// main: [0,32) scan (flag-waits) ; [32,1056) glp8 producers ; [1056,3104) gemm
__global__ __launch_bounds__(256, 4) void k_main(const float* __restrict__ X,
                                                 const float* __restrict__ Wgt,
                                                 const float* __restrict__ gb,
                                                 float* __restrict__ g,
                                                 const int* __restrict__ labels,
                                                 const int* __restrict__ in_lens,
                                                 const int* __restrict__ lab_lens,
                                                 float* __restrict__ af,
                                                 float* __restrict__ ab,
                                                 const unsigned short* __restrict__ Xbf,
                                                 const unsigned short* __restrict__ Wt,
                                                 const float* __restrict__ bvec,
                                                 float* __restrict__ pg,
                                                 int* __restrict__ cnt) {
  __shared__ __align__(16) char smem[33792];
  const int bid = blockIdx.x;
  if (bid < 32) {
    d_scan(bid, threadIdx.x, smem, g, labels, in_lens, lab_lens, af, ab, cnt);
  } else if (bid < 1056) {
    d_glp8(bid - 32, threadIdx.x, smem, X, Wgt, gb, in_lens, g, cnt);
  } else {
    d_gemm(bid - 1056, threadIdx.x, smem, Xbf, Wt, bvec, in_lens, pg);
  }
}

// tail2 (single block): Sn per sample + state-lse + final mean -> out
__global__ __launch_bounds__(256) void k_tail2(const float* __restrict__ pg,
                                               const int* __restrict__ lens,
                                               const float* __restrict__ af,
                                               const float* __restrict__ ab,
                                               float* __restrict__ out) {
  const int tid = threadIdx.x;
  const int n = tid >> 4, q = tid & 15;
  const int len = lens[n];
  __shared__ double redd[256];
  __shared__ float  redf[256];
  __shared__ double nsh[16];
  double s = 0.0;
  for (int t = q; t < len; t += 16) {
    const float4* p = (const float4*)(pg + ((size_t)(n * 512 + t)) * 32);
    float e = 0.f;
#pragma unroll
    for (int i = 0; i < 8; ++i) { float4 v = p[i]; e += v.x + v.y + v.z + v.w; }
    s += (double)__logf(e);
  }
  redd[tid] = s;
  __syncthreads();
  for (int off = 8; off > 0; off >>= 1) {
    if (q < off) redd[tid] += redd[tid + off];
    __syncthreads();
  }
  const float* f  = af + n * 320;
  const float* bb = ab + n * 320;
  float M = NEGF;
  for (int st = q; st < 257; st += 16) M = fmaxf(M, f[st] + bb[st]);
  redf[tid] = M;
  __syncthreads();
  for (int off = 8; off > 0; off >>= 1) {
    if (q < off) redf[tid] = fmaxf(redf[tid], redf[tid + off]);
    __syncthreads();
  }
  const float Mg = redf[n << 4];
  __syncthreads();   // before reusing redf
  float e = 0.f;
  for (int st = q; st < 257; st += 16) e += exp2f(f[st] + bb[st] - Mg);
  redf[tid] = e;
  __syncthreads();
  for (int off = 8; off > 0; off >>= 1) {
    if (q < off) redf[tid] += redf[tid + off];
    __syncthreads();
  }
  if (q == 0)
    nsh[n] = redd[tid] - (double)(Mg + __log2f(redf[tid])) * LN2d;
  __syncthreads();
  if (tid == 0) {
    double acc = 0.0;
    for (int i = 0; i < 16; ++i) acc += nsh[i];
    out[0] = (float)(acc * 0.0625);
  }
}

// ===========================================================================
// Fallback path (round-3 structure, validated, nats domain).
// ===========================================================================
__global__ void k_gather_w(const float* __restrict__ W,
                           const float* __restrict__ b,
                           const int* __restrict__ labels,
                           float* __restrict__ Wgt,
                           float* __restrict__ gb) {
  d_gather(blockIdx.x, threadIdx.x, W, b, labels, Wgt, gb);
}

__global__ __launch_bounds__(256) void k_glp(const float* __restrict__ X,
                                             const float* __restrict__ Wgt,
                                             const float* __restrict__ gb,
                                             const float* __restrict__ lse,
                                             const int* __restrict__ lens,
                                             float* __restrict__ g) {
  const int blk = blockIdx.x;
  const int n   = blk >> 4;
  const int t0  = (blk & 15) << 5;
  if (t0 >= lens[n]) return;
  const int m0 = n * 512 + t0;
  __shared__ float xs[32][512];
  {
    const float4* Xv = (const float4*)(X + (size_t)m0 * 512);
    float4* xsv = (float4*)(&xs[0][0]);
    for (int i = threadIdx.x; i < 32 * 128; i += 256) xsv[i] = Xv[i];
  }
  __syncthreads();
  const int j = threadIdx.x;
  if (j >= 129) return;
  const float* wp = Wgt + (size_t)(n * 512) * 132 + j;
  float acc[32];
#pragma unroll
  for (int r = 0; r < 32; ++r) acc[r] = 0.f;
  float w0 = wp[0], w1 = wp[132], w2 = wp[264], w3 = wp[396];
  for (int k4 = 0; k4 < 128; ++k4) {
    const int kn = (k4 + 1) & 127;
    float p0 = wp[(size_t)(kn * 4 + 0) * 132];
    float p1 = wp[(size_t)(kn * 4 + 1) * 132];
    float p2 = wp[(size_t)(kn * 4 + 2) * 132];
    float p3 = wp[(size_t)(kn * 4 + 3) * 132];
#pragma unroll
    for (int r = 0; r < 32; ++r) {
      float4 x4 = *(const float4*)(&xs[r][k4 << 2]);
      acc[r] = fmaf(x4.x, w0, acc[r]);
      acc[r] = fmaf(x4.y, w1, acc[r]);
      acc[r] = fmaf(x4.z, w2, acc[r]);
      acc[r] = fmaf(x4.w, w3, acc[r]);
    }
    w0 = p0; w1 = p1; w2 = p2; w3 = p3;
  }
  const float bb = gb[n * 129 + j];
#pragma unroll
  for (int r = 0; r < 32; ++r)
    g[(size_t)(m0 + r) * 132 + j] = acc[r] + bb - lse[m0 + r];
}

__global__ void k_ctc_g(const float* __restrict__ g,
                        const int* __restrict__ labels,
                        const int* __restrict__ in_lens,
                        const int* __restrict__ lab_lens,
                        float* __restrict__ nll) {
  const int n = blockIdx.x;
  const int l = threadIdx.x;
  const float* gn = g + (size_t)n * 512 * 132;
  const int len = in_lens[n];
  const int s0 = 5 * l;
  int jm[5]; bool sk[5];
#pragma unroll
  for (int i = 0; i < 5; ++i) {
    const int s = s0 + i;
    const bool valid = (s < 257);
    jm[i] = (valid && (s & 1)) ? ((s + 1) >> 1) : 0;
    sk[i] = false;
    if (valid && (s & 1) && s >= 3) {
      const int li = (s - 1) >> 1;
      const int cl = labels[n * 128 + li];
      sk[i] = (cl != 0) && (cl != labels[n * 128 + li - 1]);
    }
  }
  float a[5];
  a[0] = (l == 0) ? gn[0] : NEGF;
  a[1] = (l == 0) ? gn[1] : NEGF;
  a[2] = NEGF; a[3] = NEGF; a[4] = NEGF;
  float lp[5];
#pragma unroll
  for (int i = 0; i < 5; ++i) lp[i] = gn[132 + jm[i]];
  for (int t = 1; t < len; ++t) {
    const int tp = (t + 1 < len) ? (t + 1) : t;
    float np[5];
#pragma unroll
    for (int i = 0; i < 5; ++i) np[i] = gn[(size_t)tp * 132 + jm[i]];
    float a3p = __shfl_up(a[3], 1);
    float a4p = __shfl_up(a[4], 1);
    if (l == 0) { a3p = NEGF; a4p = NEGF; }
    const float b0 = lae3n(a[0], a4p,  sk[0] ? a3p  : NEGF) + lp[0];
    const float b1 = lae3n(a[1], a[0], sk[1] ? a4p  : NEGF) + lp[1];
    const float b2 = lae3n(a[2], a[1], sk[2] ? a[0] : NEGF) + lp[2];
    const float b3 = lae3n(a[3], a[2], sk[3] ? a[1] : NEGF) + lp[3];
    const float b4 = lae3n(a[4], a[3], sk[4] ? a[2] : NEGF) + lp[4];
    a[0] = b0; a[1] = b1; a[2] = b2; a[3] = b3; a[4] = b4;
#pragma unroll
    for (int i = 0; i < 5; ++i) lp[i] = np[i];
  }
  __shared__ float al[320];
#pragma unroll
  for (int i = 0; i < 5; ++i) al[s0 + i] = a[i];
  __syncthreads();
  if (l == 0) {
    const int ll  = lab_lens[n];
    const int idx = 2 * ll;
    const float e1 = al[idx], e2 = al[idx - 1];
    const float m = fmaxf(e1, e2);
    const float r = m + __logf(__expf(e1 - m) + __expf(e2 - m));
    nll[n] = -r;
  }
}

__global__ __launch_bounds__(512, 2) void k_lse(const float* __restrict__ X,
                                                const float* __restrict__ W,
                                                const float* __restrict__ b,
                                                const int* __restrict__ lens,
                                                float* __restrict__ lse,
                                                float* __restrict__ red_g) {
  const int blk = blockIdx.x;
  const int n   = blk >> 4;
  const int t0  = (blk & 15) << 5;
  if (t0 >= lens[n]) return;
  const int m0 = n * 512 + t0;
  __shared__ float xs[32][512];
  {
    const float4* Xv = (const float4*)(X + (size_t)m0 * 512);
    float4* xsv = (float4*)(&xs[0][0]);
    for (int i = threadIdx.x; i < 32 * 128; i += 512) xsv[i] = Xv[i];
  }
  float* redb = red_g + (size_t)blk * 256;
  for (int i = threadIdx.x; i < 256; i += 512) redb[i] = 0.f;
  __syncthreads();
  const int wave = threadIdx.x >> 6;
  const int lane = threadIdx.x & 63;
  for (int j = 0; j < 4; ++j) {
    const int v = (j << 10) + (threadIdx.x << 1);
    const float* Wv = W + v;
    float2 acc[32];
#pragma unroll
    for (int r = 0; r < 32; ++r) acc[r] = make_float2(0.f, 0.f);
    float2 w0 = *(const float2*)(Wv + 0 * 4096);
    float2 w1 = *(const float2*)(Wv + 1 * 4096);
    float2 w2 = *(const float2*)(Wv + 2 * 4096);
    float2 w3 = *(const float2*)(Wv + 3 * 4096);
    for (int k4 = 0; k4 < 128; ++k4) {
      const int kn = (k4 + 1) & 127;
      float2 p0 = *(const float2*)(Wv + (kn * 4 + 0) * 4096);
      float2 p1 = *(const float2*)(Wv + (kn * 4 + 1) * 4096);
      float2 p2 = *(const float2*)(Wv + (kn * 4 + 2) * 4096);
      float2 p3 = *(const float2*)(Wv + (kn * 4 + 3) * 4096);
#pragma unroll
      for (int r = 0; r < 32; ++r) {
        float4 x4 = *(const float4*)(&xs[r][k4 << 2]);
        acc[r].x = fmaf(x4.x, w0.x, acc[r].x);
        acc[r].y = fmaf(x4.x, w0.y, acc[r].y);
        acc[r].x = fmaf(x4.y, w1.x, acc[r].x);
        acc[r].y = fmaf(x4.y, w1.y, acc[r].y);
        acc[r].x = fmaf(x4.z, w2.x, acc[r].x);
        acc[r].y = fmaf(x4.z, w2.y, acc[r].y);
        acc[r].x = fmaf(x4.w, w3.x, acc[r].x);
        acc[r].y = fmaf(x4.w, w3.y, acc[r].y);
      }
      w0 = p0; w1 = p1; w2 = p2; w3 = p3;
    }
    const float2 bb = *(const float2*)(b + v);
#pragma unroll
    for (int r = 0; r < 32; ++r) {
      float e = __expf(acc[r].x + bb.x) + __expf(acc[r].y + bb.y);
#pragma unroll
      for (int off = 32; off > 0; off >>= 1) e += __shfl_xor(e, off);
      if (lane == 0) redb[wave * 32 + r] += e;
    }
  }
  __syncthreads();
  if (threadIdx.x < 32) {
    float s = 0.f;
#pragma unroll
    for (int w = 0; w < 8; ++w) s += redb[w * 32 + threadIdx.x];
    lse[m0 + threadIdx.x] = __logf(s);
  }
}

__global__ void k_finish(const float* __restrict__ nll, float* __restrict__ out) {
  const int l = threadIdx.x;
  float v = (l < 16) ? nll[l] : 0.f;
#pragma unroll
  for (int off = 8; off > 0; off >>= 1) v += __shfl_down(v, off);
  if (l == 0) out[0] = v * 0.0625f;
}

// ---------------------------------------------------------------------------
extern "C" void kernel_launch(void* const* d_in, const int* in_sizes, int n_in,
                              void* d_out, int out_size, void* d_ws, size_t ws_size,
                              hipStream_t stream) {
  const float* X        = (const float*)d_in[0];   // (16,512,512)
  const float* W        = (const float*)d_in[1];   // (512,4096)
  const float* b        = (const float*)d_in[2];   // (4096)
  const int*   in_lens  = (const int*)d_in[3];     // (16)
  const int*   labels   = (const int*)d_in[4];     // (16,128)
  const int*   lab_lens = (const int*)d_in[5];     // (16)
  float* out = (float*)d_out;
  char* wsb = (char*)d_ws;

  const size_t NEED = 34906240;
  if (ws_size >= NEED) {
    int*   cnt = (int*)(wsb + 0);            // 256 flag slots (zeroed in prep1)
    float* pg  = (float*)(wsb + 32768);      // 8192*32 f
    float* Wgt = (float*)(wsb + 1081344);    // 16*512*132 f
    float* gb  = (float*)(wsb + 5406720);    // 16*129 f
    float* g   = (float*)(wsb + 5414976);    // 16*512*132 f
    unsigned short* Xbf = (unsigned short*)(wsb + 9740416);   // 8 MB
    unsigned short* Wt  = (unsigned short*)(wsb + 18129024);  // 4 MB
    float* af = (float*)(wsb + 26517632);                     // 16*320 f
    float* ab = (float*)(wsb + 26517632 + 20480);

    k_prep1<<<dim3(6657), dim3(256), 0, stream>>>(X, Xbf, W, b, labels, Wgt,
                                                  gb, Wt, cnt);
    k_main<<<dim3(3104), dim3(256), 0, stream>>>(X, Wgt, gb, g, labels,
                                                 in_lens, lab_lens, af, ab,
                                                 Xbf, Wt, b, pg, cnt);
    k_tail2<<<dim3(1), dim3(256), 0, stream>>>(pg, in_lens, af, ab, out);
  } else {
    float* ws    = (float*)d_ws;
    float* lse   = ws;
    float* red_g = ws + 8192;
    float* Wgt   = ws + 8192 + 65536;
    float* gb    = Wgt + 1081344;
    float* g     = gb + 2064;
    float* nll   = g + 1081344;
    k_lse<<<dim3(256), dim3(512), 0, stream>>>(X, W, b, in_lens, lse, red_g);
    k_gather_w<<<dim3(2048), dim3(256), 0, stream>>>(W, b, labels, Wgt, gb);
    k_glp<<<dim3(256), dim3(256), 0, stream>>>(X, Wgt, gb, lse, in_lens, g);
    k_ctc_g<<<dim3(16), dim3(64), 0, stream>>>(g, labels, in_lens, lab_lens, nll);
    k_finish<<<dim3(1), dim3(64), 0, stream>>>(nll, out);
  }
}

// Round 18
// 194.169 us; speedup vs baseline: 1.5183x; 1.5183x over previous
//
#include <hip/hip_runtime.h>

#define NEGF (-1e30f)
#define LOG2E 1.4426950408889634f
#define LN2d  0.6931471805599453

typedef __attribute__((ext_vector_type(8))) short bf16x8;
typedef __attribute__((ext_vector_type(4))) float f32x4;

__device__ __forceinline__ unsigned short f2bf(float x) {
  unsigned u = __float_as_uint(x);
  unsigned r = (u + 0x7FFFu + ((u >> 16) & 1u)) >> 16;
  return (unsigned short)r;
}

// ===========================================================================
// Device bodies
// ===========================================================================

__device__ __forceinline__ void d_cvtx(int bid, int tid,
                                       const float* __restrict__ X,
                                       unsigned short* __restrict__ Xbf) {
  const int i = bid * 256 + tid;
  float4 v = ((const float4*)X)[i];
  ushort4 h;
  h.x = f2bf(v.x); h.y = f2bf(v.y); h.z = f2bf(v.z); h.w = f2bf(v.w);
  ((ushort4*)Xbf)[i] = h;
}

__device__ __forceinline__ void d_gather(int bid, int tid,
                                         const float* __restrict__ W,
                                         const float* __restrict__ b,
                                         const int* __restrict__ labels,
                                         float* __restrict__ Wgt,
                                         float* __restrict__ gb) {
  const int n  = bid >> 7;
  const int kc = bid & 127;
  const int k0 = kc << 2;
  for (int idx = tid; idx < 4 * 129; idx += 256) {
    const int kk = idx / 129;
    const int j  = idx - kk * 129;
    const int c  = (j == 0) ? 0 : labels[n * 128 + (j - 1)];
    const int k  = k0 + kk;
    Wgt[((size_t)(n * 512 + k)) * 132 + j] = W[(size_t)k * 4096 + c];
    if (kc == 0 && kk == 0) gb[n * 129 + j] = b[c];
  }
}

__device__ __forceinline__ void d_wtrans(int bid, int tid, char* smem,
                                         const float* __restrict__ W,
                                         unsigned short* __restrict__ Wt) {
  float (*tile)[65] = (float (*)[65])smem;
  const int kb = bid & 7;
  const int vb = bid >> 3;
  const int k0 = kb << 6, v0 = vb << 6;
#pragma unroll
  for (int it = 0; it < 16; ++it) {
    const int idx = it * 256 + tid;
    const int r = idx >> 6, c = idx & 63;
    tile[r][c] = W[(size_t)(k0 + r) * 4096 + v0 + c];
  }
  __syncthreads();
#pragma unroll
  for (int it = 0; it < 16; ++it) {
    const int idx = it * 256 + tid;
    const int vr = idx >> 6, kc = idx & 63;
    Wt[(size_t)(v0 + vr) * 512 + k0 + kc] = f2bf(tile[kc][vr]);
  }
}

// ---- gemm body (bf16 MFMA, swizzled, validated r12) ----------------------
__device__ __forceinline__ void stage_tile(const unsigned short* __restrict__ src,
                                           int r0, char* ldsbase, int wave,
                                           int tid, int kbyte) {
#pragma unroll
  for (int j = 0; j < 2; ++j) {
    const int chunk = (tid & 3) ^ ((tid >> 3) & 3);
    const char* gp = (const char*)src +
        (size_t)(r0 + j * 64 + (tid >> 2)) * 1024 + kbyte + chunk * 16;
    char* lp = ldsbase + j * 4096 + wave * 1024;
    __builtin_amdgcn_global_load_lds(
        (const __attribute__((address_space(1))) unsigned int*)gp,
        (__attribute__((address_space(3))) unsigned int*)lp, 16, 0, 0);
  }
}

__device__ __forceinline__ void d_gemm(int gid, int tid, char* smem,
                                       const unsigned short* __restrict__ Xbf,
                                       const unsigned short* __restrict__ Wt,
                                       const float* __restrict__ bvec,
                                       const int* __restrict__ lens,
                                       float* __restrict__ pg) {
  const int bm = gid >> 5;
  const int bn = gid & 31;
  const int n  = bm >> 2;
  const int t0 = (bm & 3) << 7;
  if (t0 >= lens[n]) return;
  const int m0 = bm << 7;
  const int v0 = bn << 7;

  const int wave = tid >> 6;
  const int lane = tid & 63;
  const int lrow = lane & 15;
  const int lk   = (lane >> 4) * 16;
  const int lks  = lk ^ (((lrow >> 1) & 3) << 4);
  const int wr   = wave >> 1;
  const int wn   = wave & 1;

  f32x4 acc[4][4];
#pragma unroll
  for (int mi = 0; mi < 4; ++mi)
#pragma unroll
    for (int ni = 0; ni < 4; ++ni) acc[mi][ni] = (f32x4){0.f, 0.f, 0.f, 0.f};

  {
    char* buf = smem;
    stage_tile(Xbf, m0, buf + 0,    wave, tid, 0);
    stage_tile(Wt,  v0, buf + 8192, wave, tid, 0);
  }
  __syncthreads();

  int cur = 0;
  for (int kk = 0; kk < 16; ++kk) {
    if (kk < 15) {
      char* nbuf = smem + (cur ^ 1) * 16384;
      const int kb = (kk + 1) << 6;
      stage_tile(Xbf, m0, nbuf + 0,    wave, tid, kb);
      stage_tile(Wt,  v0, nbuf + 8192, wave, tid, kb);
    }
    const char* buf = smem + cur * 16384;
    bf16x8 ah[4], bh[4];
#pragma unroll
    for (int mi = 0; mi < 4; ++mi) {
      const int off = (wr * 64 + mi * 16 + lrow) * 64 + lks;
      ah[mi] = *(const bf16x8*)(buf + off);
    }
#pragma unroll
    for (int ni = 0; ni < 4; ++ni) {
      const int off = (wn * 64 + ni * 16 + lrow) * 64 + lks;
      bh[ni] = *(const bf16x8*)(buf + 8192 + off);
    }
#pragma unroll
    for (int mi = 0; mi < 4; ++mi)
#pragma unroll
      for (int ni = 0; ni < 4; ++ni)
        acc[mi][ni] = __builtin_amdgcn_mfma_f32_16x16x32_bf16(ah[mi], bh[ni], acc[mi][ni], 0, 0, 0);
    __syncthreads();
    cur ^= 1;
  }

  const float lg2e = LOG2E;
  float bias[4];
#pragma unroll
  for (int ni = 0; ni < 4; ++ni) bias[ni] = bvec[v0 + wn * 64 + ni * 16 + lrow];
  float* part = (float*)(smem + 32768);
#pragma unroll
  for (int mi = 0; mi < 4; ++mi)
#pragma unroll
    for (int reg = 0; reg < 4; ++reg) {
      float s = 0.f;
#pragma unroll
      for (int ni = 0; ni < 4; ++ni)
        s += exp2f((acc[mi][ni][reg] + bias[ni]) * lg2e);
#pragma unroll
      for (int msk = 1; msk < 16; msk <<= 1) s += __shfl_xor(s, msk);
      if (lrow == 0)
        part[(wr * 64 + mi * 16 + (lane >> 4) * 4 + reg) * 2 + wn] = s;
    }
  __syncthreads();
  if (tid < 128)
    pg[(size_t)(m0 + tid) * 32 + bn] = part[tid * 2 + 0] + part[tid * 2 + 1];
}

// ---- CTC scan body (fwd/bwd split, LOG2 domain, validated r15/r16) -------
__device__ __forceinline__ float lae32(float x, float y, float z) {
  float m = fmaxf(fmaxf(x, y), z);
  float e = exp2f(x - m) + exp2f(y - m) + exp2f(z - m);
  return m + __log2f(e);
}

__device__ __forceinline__ float lae3n(float x, float y, float z) {
  float m = fmaxf(fmaxf(x, y), z);
  float e = __expf(x - m) + __expf(y - m) + __expf(z - m);
  return m + __logf(e);
}

__device__ __forceinline__ void stage32(const float* __restrict__ gsrc,
                                        char* ldsbase, int tid, int wave) {
#pragma unroll
  for (int k = 0; k < 4; ++k) {
    const char* gp = (const char*)gsrc + k * 4096 + (size_t)tid * 16;
    char* lp = ldsbase + k * 4096 + wave * 1024;
    __builtin_amdgcn_global_load_lds(
        (const __attribute__((address_space(1))) unsigned int*)gp,
        (__attribute__((address_space(3))) unsigned int*)lp, 16, 0, 0);
  }
  if (tid < 32) {
    const char* gp = (const char*)gsrc + 16384 + (size_t)tid * 16;
    char* lp = ldsbase + 16384;
    __builtin_amdgcn_global_load_lds(
        (const __attribute__((address_space(1))) unsigned int*)gp,
        (__attribute__((address_space(3))) unsigned int*)lp, 16, 0, 0);
  }
}

__device__ void d_scan(int sbid, int tid, char* smem,
                       const float* __restrict__ g,
                       const int* __restrict__ labels,
                       const int* __restrict__ in_lens,
                       const int* __restrict__ lab_lens,
                       float* __restrict__ af,
                       float* __restrict__ ab) {
  const int n    = sbid >> 1;
  const int dir  = sbid & 1;
  const int wave = tid >> 6;
  const int l    = tid & 63;
  const int len  = in_lens[n];
  const int tm   = len >> 1;
  const float* gn = g + (size_t)n * 512 * 132;
  const int s0 = 5 * l;

  int jm0, jm1, jm2, jm3, jm4;
  {
    int jmv[5];
#pragma unroll
    for (int i = 0; i < 5; ++i) {
      const int s = s0 + i;
      jmv[i] = (s < 257 && (s & 1)) ? ((s + 1) >> 1) : 0;
    }
    jm0 = jmv[0]; jm1 = jmv[1]; jm2 = jmv[2]; jm3 = jmv[3]; jm4 = jmv[4];
  }

  if (dir == 0) {
    bool sk0, sk1, sk2, sk3, sk4;
    {
      bool skv[5];
#pragma unroll
      for (int i = 0; i < 5; ++i) {
        const int s = s0 + i;
        skv[i] = false;
        if (s < 257 && (s & 1) && s >= 3) {
          const int li = (s - 1) >> 1;
          const int cl = labels[n * 128 + li];
          skv[i] = (cl != 0) && (cl != labels[n * 128 + li - 1]);
        }
      }
      sk0 = skv[0]; sk1 = skv[1]; sk2 = skv[2]; sk3 = skv[3]; sk4 = skv[4];
    }
    stage32(gn, smem, tid, wave);
    __syncthreads();

    float a0 = NEGF, a1 = NEGF, a2 = NEGF, a3 = NEGF, a4 = NEGF;
    if (tid < 64 && l == 0) {
      const float* B0 = (const float*)smem;
      a0 = B0[0]; a1 = B0[1];
    }
    float a3p = NEGF, a4p = NEGF;

    int t = 1, c = 0;
    while (true) {
      const bool more = ((c + 1) << 5) <= tm;
      if (more)
        stage32(gn + (size_t)((c + 1) << 5) * 132,
                smem + ((c + 1) & 1) * 16896, tid, wave);
      if (tid < 64) {
        const float* B = (const float*)(smem + (c & 1) * 16896);
        const int ce = (c << 5) + 31;
        const int tend = (tm < ce) ? tm : ce;
        int ro = (t - (c << 5)) * 132;
        float p0 = B[ro + jm0], p1 = B[ro + jm1], p2 = B[ro + jm2],
              p3 = B[ro + jm3], p4 = B[ro + jm4];
        for (; t <= tend; ++t) {
          const int ro2 = (t < tend) ? ro + 132 : ro;
          const float q0 = B[ro2 + jm0];
          const float q1 = B[ro2 + jm1];
          const float q2 = B[ro2 + jm2];
          const float q3 = B[ro2 + jm3];
          const float q4 = B[ro2 + jm4];
          float x3 = a3p, x4 = a4p;
          if (l == 0) { x3 = NEGF; x4 = NEGF; }
          const float n3 = lae32(a3, a2, sk3 ? a1 : NEGF) + p3;
          const float n4 = lae32(a4, a3, sk4 ? a2 : NEGF) + p4;
          a3p = __shfl_up(n3, 1);
          a4p = __shfl_up(n4, 1);
          const float n0 = lae32(a0, x4, sk0 ? x3 : NEGF) + p0;
          const float n1 = lae32(a1, a0, sk1 ? x4 : NEGF) + p1;
          const float n2 = lae32(a2, a1, sk2 ? a0 : NEGF) + p2;
          a0 = n0; a1 = n1; a2 = n2; a3 = n3; a4 = n4;
          p0 = q0; p1 = q1; p2 = q2; p3 = q3; p4 = q4;
          ro = ro2;
        }
      }
      if (!more) break;
      __syncthreads();
      ++c;
    }
    if (tid < 64) {
      float* o = af + n * 320 + s0;
      o[0] = a0; o[1] = a1; o[2] = a2; o[3] = a3; o[4] = a4;
    }
  } else {
    bool skd0, skd1, skd2, skd3, skd4;
    {
      bool skv[5];
#pragma unroll
      for (int i = 0; i < 5; ++i) {
        const int s2 = s0 + i + 2;
        skv[i] = false;
        if (s2 < 257 && (s2 & 1) && s2 >= 3) {
          const int li = (s2 - 1) >> 1;
          const int cl = labels[n * 128 + li];
          skv[i] = (cl != 0) && (cl != labels[n * 128 + li - 1]);
        }
      }
      skd0 = skv[0]; skd1 = skv[1]; skd2 = skv[2]; skd3 = skv[3]; skd4 = skv[4];
    }
    int c = (len - 1) >> 5;
    stage32(gn + (size_t)(c << 5) * 132, smem + (c & 1) * 16896, tid, wave);
    __syncthreads();

    float b0, b1, b2, b3, b4;
    {
      const int ll = lab_lens[n];
      const int i1 = 2 * ll, i2 = 2 * ll - 1;
      b0 = (s0 + 0 == i1 || s0 + 0 == i2) ? 0.f : NEGF;
      b1 = (s0 + 1 == i1 || s0 + 1 == i2) ? 0.f : NEGF;
      b2 = (s0 + 2 == i1 || s0 + 2 == i2) ? 0.f : NEGF;
      b3 = (s0 + 3 == i1 || s0 + 3 == i2) ? 0.f : NEGF;
      b4 = (s0 + 4 == i1 || s0 + 4 == i2) ? 0.f : NEGF;
    }

    int t = len - 2;
    while (true) {
      const bool more = (c << 5) > tm + 1;
      if (more)
        stage32(gn + (size_t)((c - 1) << 5) * 132,
                smem + ((c - 1) & 1) * 16896, tid, wave);
      if (tid < 64) {
        const float* B = (const float*)(smem + (c & 1) * 16896);
        const int cl0 = (c << 5) - 1;
        const int tlo = (tm > cl0) ? tm : cl0;
        int ro = (t + 1 - (c << 5)) * 132;
        float p0 = B[ro + jm0], p1 = B[ro + jm1], p2 = B[ro + jm2],
              p3 = B[ro + jm3], p4 = B[ro + jm4];
        for (; t >= tlo; --t) {
          const int ro2 = (t - 1 >= tlo) ? ro - 132 : ro;
          const float q0 = B[ro2 + jm0];
          const float q1 = B[ro2 + jm1];
          const float q2 = B[ro2 + jm2];
          const float q3 = B[ro2 + jm3];
          const float q4 = B[ro2 + jm4];
          const float c0 = b0 + p0;
          const float c1 = b1 + p1;
          float c5 = __shfl_down(c0, 1);
          float c6 = __shfl_down(c1, 1);
          const float c2 = b2 + p2;
          const float c3 = b3 + p3;
          const float c4 = b4 + p4;
          const float m0n = lae32(c0, c1, skd0 ? c2 : NEGF);
          const float m1n = lae32(c1, c2, skd1 ? c3 : NEGF);
          const float m2n = lae32(c2, c3, skd2 ? c4 : NEGF);
          if (l == 63) { c5 = NEGF; c6 = NEGF; }
          const float m3n = lae32(c3, c4, skd3 ? c5 : NEGF);
          const float m4n = lae32(c4, c5, skd4 ? c6 : NEGF);
          b0 = m0n; b1 = m1n; b2 = m2n; b3 = m3n; b4 = m4n;
          p0 = q0; p1 = q1; p2 = q2; p3 = q3; p4 = q4;
          ro = ro2;
        }
      }
      if (!more) break;
      __syncthreads();
      --c;
    }
    if (tid < 64) {
      float* o = ab + n * 320 + s0;
      o[0] = b0; o[1] = b1; o[2] = b2; o[3] = b3; o[4] = b4;
    }
  }
}

// ===========================================================================
// Launchers (main path) — r16 structure + merged tail
// ===========================================================================

// prep1: [0,4096) cvtx ; [4096,6144) gather ; [6144,6656) wtrans
__global__ __launch_bounds__(256) void k_prep1(const float* __restrict__ X,
                                               unsigned short* __restrict__ Xbf,
                                               const float* __restrict__ W,
                                               const float* __restrict__ b,
                                               const int* __restrict__ labels,
                                               float* __restrict__ Wgt,
                                               float* __restrict__ gb,
                                               unsigned short* __restrict__ Wt) {
  __shared__ __align__(16) char smem[16640];
  const int bid = blockIdx.x;
  if (bid < 4096)      d_cvtx(bid, threadIdx.x, X, Xbf);
  else if (bid < 6144) d_gather(bid - 4096, threadIdx.x, W, b, labels, Wgt, gb);
  else                 d_wtrans(bid - 6144, threadIdx.x, smem, W, Wt);
}

// glp8: 8 rows/block (1024 blocks, all co-resident) — log2-domain raw logits.
__global__ __launch_bounds__(256) void k_glp8(const float* __restrict__ X,
                                              const float* __restrict__ Wgt,
                                              const float* __restrict__ gb,
                                              const int* __restrict__ lens,
                                              float* __restrict__ g) {
  __shared__ float xs[8][512];   // 16 KB
  const int bid = blockIdx.x;
  const int n  = bid >> 6;
  const int r0 = (bid & 63) << 3;
  if (r0 >= lens[n]) return;
  const int m0 = n * 512 + r0;
  {
    const float4* Xv = (const float4*)(X + (size_t)m0 * 512);
    float4* xsv = (float4*)(&xs[0][0]);
    for (int i = threadIdx.x; i < 8 * 128; i += 256) xsv[i] = Xv[i];
  }
  __syncthreads();
  const int j = threadIdx.x;
  if (j >= 129) return;
  const float* wp = Wgt + (size_t)(n * 512) * 132 + j;
  float acc[8];
#pragma unroll
  for (int r = 0; r < 8; ++r) acc[r] = 0.f;
  float w0 = wp[0], w1 = wp[132], w2 = wp[264], w3 = wp[396];
  for (int k4 = 0; k4 < 128; ++k4) {
    const int kn = (k4 + 1) & 127;
    float p0 = wp[(size_t)(kn * 4 + 0) * 132];
    float p1 = wp[(size_t)(kn * 4 + 1) * 132];
    float p2 = wp[(size_t)(kn * 4 + 2) * 132];
    float p3 = wp[(size_t)(kn * 4 + 3) * 132];
#pragma unroll
    for (int r = 0; r < 8; ++r) {
      float4 x4 = *(const float4*)(&xs[r][k4 << 2]);
      acc[r] = fmaf(x4.x, w0, acc[r]);
      acc[r] = fmaf(x4.y, w1, acc[r]);
      acc[r] = fmaf(x4.z, w2, acc[r]);
      acc[r] = fmaf(x4.w, w3, acc[r]);
    }
    w0 = p0; w1 = p1; w2 = p2; w3 = p3;
  }
  const float bb = gb[n * 129 + j];
#pragma unroll
  for (int r = 0; r < 8; ++r)
    g[(size_t)(m0 + r) * 132 + j] = (acc[r] + bb) * LOG2E;
}

// main: blocks [0,32) CTC scan ; [32,2080) gemm  (r16 structure)
__global__ __launch_bounds__(256, 4) void k_main(const float* __restrict__ g,
                                                 const int* __restrict__ labels,
                                                 const int* __restrict__ in_lens,
                                                 const int* __restrict__ lab_lens,
                                                 float* __restrict__ af,
                                                 float* __restrict__ ab,
                                                 const unsigned short* __restrict__ Xbf,
                                                 const unsigned short* __restrict__ Wt,
                                                 const float* __restrict__ bvec,
                                                 float* __restrict__ pg) {
  __shared__ __align__(16) char smem[33792];
  const int bid = blockIdx.x;
  if (bid < 32) {
    d_scan(bid, threadIdx.x, smem, g, labels, in_lens, lab_lens, af, ab);
  } else {
    d_gemm(bid - 32, threadIdx.x, smem, Xbf, Wt, bvec, in_lens, pg);
  }
}

// tail2 (single block): Sn per sample + state-lse + final mean -> out
// (validated inside r17's run)
__global__ __launch_bounds__(256) void k_tail2(const float* __restrict__ pg,
                                               const int* __restrict__ lens,
                                               const float* __restrict__ af,
                                               const float* __restrict__ ab,
                                               float* __restrict__ out) {
  const int tid = threadIdx.x;
  const int n = tid >> 4, q = tid & 15;
  const int len = lens[n];
  __shared__ double redd[256];
  __shared__ float  redf[256];
  __shared__ double nsh[16];
  double s = 0.0;
  for (int t = q; t < len; t += 16) {
    const float4* p = (const float4*)(pg + ((size_t)(n * 512 + t)) * 32);
    float e = 0.f;
#pragma unroll
    for (int i = 0; i < 8; ++i) { float4 v = p[i]; e += v.x + v.y + v.z + v.w; }
    s += (double)__logf(e);
  }
  redd[tid] = s;
  __syncthreads();
  for (int off = 8; off > 0; off >>= 1) {
    if (q < off) redd[tid] += redd[tid + off];
    __syncthreads();
  }
  const float* f  = af + n * 320;
  const float* bb = ab + n * 320;
  float M = NEGF;
  for (int st = q; st < 257; st += 16) M = fmaxf(M, f[st] + bb[st]);
  redf[tid] = M;
  __syncthreads();
  for (int off = 8; off > 0; off >>= 1) {
    if (q < off) redf[tid] = fmaxf(redf[tid], redf[tid + off]);
    __syncthreads();
  }
  const float Mg = redf[n << 4];
  __syncthreads();   // before reusing redf
  float e = 0.f;
  for (int st = q; st < 257; st += 16) e += exp2f(f[st] + bb[st] - Mg);
  redf[tid] = e;
  __syncthreads();
  for (int off = 8; off > 0; off >>= 1) {
    if (q < off) redf[tid] += redf[tid + off];
    __syncthreads();
  }
  if (q == 0)
    nsh[n] = redd[tid] - (double)(Mg + __log2f(redf[tid])) * LN2d;
  __syncthreads();
  if (tid == 0) {
    double acc = 0.0;
    for (int i = 0; i < 16; ++i) acc += nsh[i];
    out[0] = (float)(acc * 0.0625);
  }
}

// ===========================================================================
// Fallback path (round-3 structure, validated, nats domain).
// ===========================================================================
__global__ void k_gather_w(const float* __restrict__ W,
                           const float* __restrict__ b,
                           const int* __restrict__ labels,
                           float* __restrict__ Wgt,
                           float* __restrict__ gb) {
  d_gather(blockIdx.x, threadIdx.x, W, b, labels, Wgt, gb);
}

__global__ __launch_bounds__(256) void k_glp(const float* __restrict__ X,
                                             const float* __restrict__ Wgt,
                                             const float* __restrict__ gb,
                                             const float* __restrict__ lse,
                                             const int* __restrict__ lens,
                                             float* __restrict__ g) {
  const int blk = blockIdx.x;
  const int n   = blk >> 4;
  const int t0  = (blk & 15) << 5;
  if (t0 >= lens[n]) return;
  const int m0 = n * 512 + t0;
  __shared__ float xs[32][512];
  {
    const float4* Xv = (const float4*)(X + (size_t)m0 * 512);
    float4* xsv = (float4*)(&xs[0][0]);
    for (int i = threadIdx.x; i < 32 * 128; i += 256) xsv[i] = Xv[i];
  }
  __syncthreads();
  const int j = threadIdx.x;
  if (j >= 129) return;
  const float* wp = Wgt + (size_t)(n * 512) * 132 + j;
  float acc[32];
#pragma unroll
  for (int r = 0; r < 32; ++r) acc[r] = 0.f;
  float w0 = wp[0], w1 = wp[132], w2 = wp[264], w3 = wp[396];
  for (int k4 = 0; k4 < 128; ++k4) {
    const int kn = (k4 + 1) & 127;
    float p0 = wp[(size_t)(kn * 4 + 0) * 132];
    float p1 = wp[(size_t)(kn * 4 + 1) * 132];
    float p2 = wp[(size_t)(kn * 4 + 2) * 132];
    float p3 = wp[(size_t)(kn * 4 + 3) * 132];
#pragma unroll
    for (int r = 0; r < 32; ++r) {
      float4 x4 = *(const float4*)(&xs[r][k4 << 2]);
      acc[r] = fmaf(x4.x, w0, acc[r]);
      acc[r] = fmaf(x4.y, w1, acc[r]);
      acc[r] = fmaf(x4.z, w2, acc[r]);
      acc[r] = fmaf(x4.w, w3, acc[r]);
    }
    w0 = p0; w1 = p1; w2 = p2; w3 = p3;
  }
  const float bb = gb[n * 129 + j];
#pragma unroll
  for (int r = 0; r < 32; ++r)
    g[(size_t)(m0 + r) * 132 + j] = acc[r] + bb - lse[m0 + r];
}

__global__ void k_ctc_g(const float* __restrict__ g,
                        const int* __restrict__ labels,
                        const int* __restrict__ in_lens,
                        const int* __restrict__ lab_lens,
                        float* __restrict__ nll) {
  const int n = blockIdx.x;
  const int l = threadIdx.x;
  const float* gn = g + (size_t)n * 512 * 132;
  const int len = in_lens[n];
  const int s0 = 5 * l;
  int jm[5]; bool sk[5];
#pragma unroll
  for (int i = 0; i < 5; ++i) {
    const int s = s0 + i;
    const bool valid = (s < 257);
    jm[i] = (valid && (s & 1)) ? ((s + 1) >> 1) : 0;
    sk[i] = false;
    if (valid && (s & 1) && s >= 3) {
      const int li = (s - 1) >> 1;
      const int cl = labels[n * 128 + li];
      sk[i] = (cl != 0) && (cl != labels[n * 128 + li - 1]);
    }
  }
  float a[5];
  a[0] = (l == 0) ? gn[0] : NEGF;
  a[1] = (l == 0) ? gn[1] : NEGF;
  a[2] = NEGF; a[3] = NEGF; a[4] = NEGF;
  float lp[5];
#pragma unroll
  for (int i = 0; i < 5; ++i) lp[i] = gn[132 + jm[i]];
  for (int t = 1; t < len; ++t) {
    const int tp = (t + 1 < len) ? (t + 1) : t;
    float np[5];
#pragma unroll
    for (int i = 0; i < 5; ++i) np[i] = gn[(size_t)tp * 132 + jm[i]];
    float a3p = __shfl_up(a[3], 1);
    float a4p = __shfl_up(a[4], 1);
    if (l == 0) { a3p = NEGF; a4p = NEGF; }
    const float b0 = lae3n(a[0], a4p,  sk[0] ? a3p  : NEGF) + lp[0];
    const float b1 = lae3n(a[1], a[0], sk[1] ? a4p  : NEGF) + lp[1];
    const float b2 = lae3n(a[2], a[1], sk[2] ? a[0] : NEGF) + lp[2];
    const float b3 = lae3n(a[3], a[2], sk[3] ? a[1] : NEGF) + lp[3];
    const float b4 = lae3n(a[4], a[3], sk[4] ? a[2] : NEGF) + lp[4];
    a[0] = b0; a[1] = b1; a[2] = b2; a[3] = b3; a[4] = b4;
#pragma unroll
    for (int i = 0; i < 5; ++i) lp[i] = np[i];
  }
  __shared__ float al[320];
#pragma unroll
  for (int i = 0; i < 5; ++i) al[s0 + i] = a[i];
  __syncthreads();
  if (l == 0) {
    const int ll  = lab_lens[n];
    const int idx = 2 * ll;
    const float e1 = al[idx], e2 = al[idx - 1];
    const float m = fmaxf(e1, e2);
    const float r = m + __logf(__expf(e1 - m) + __expf(e2 - m));
    nll[n] = -r;
  }
}

__global__ __launch_bounds__(512, 2) void k_lse(const float* __restrict__ X,
                                                const float* __restrict__ W,
                                                const float* __restrict__ b,
                                                const int* __restrict__ lens,
                                                float* __restrict__ lse,
                                                float* __restrict__ red_g) {
  const int blk = blockIdx.x;
  const int n   = blk >> 4;
  const int t0  = (blk & 15) << 5;
  if (t0 >= lens[n]) return;
  const int m0 = n * 512 + t0;
  __shared__ float xs[32][512];
  {
    const float4* Xv = (const float4*)(X + (size_t)m0 * 512);
    float4* xsv = (float4*)(&xs[0][0]);
    for (int i = threadIdx.x; i < 32 * 128; i += 512) xsv[i] = Xv[i];
  }
  float* redb = red_g + (size_t)blk * 256;
  for (int i = threadIdx.x; i < 256; i += 512) redb[i] = 0.f;
  __syncthreads();
  const int wave = threadIdx.x >> 6;
  const int lane = threadIdx.x & 63;
  for (int j = 0; j < 4; ++j) {
    const int v = (j << 10) + (threadIdx.x << 1);
    const float* Wv = W + v;
    float2 acc[32];
#pragma unroll
    for (int r = 0; r < 32; ++r) acc[r] = make_float2(0.f, 0.f);
    float2 w0 = *(const float2*)(Wv + 0 * 4096);
    float2 w1 = *(const float2*)(Wv + 1 * 4096);
    float2 w2 = *(const float2*)(Wv + 2 * 4096);
    float2 w3 = *(const float2*)(Wv + 3 * 4096);
    for (int k4 = 0; k4 < 128; ++k4) {
      const int kn = (k4 + 1) & 127;
      float2 p0 = *(const float2*)(Wv + (kn * 4 + 0) * 4096);
      float2 p1 = *(const float2*)(Wv + (kn * 4 + 1) * 4096);
      float2 p2 = *(const float2*)(Wv + (kn * 4 + 2) * 4096);
      float2 p3 = *(const float2*)(Wv + (kn * 4 + 3) * 4096);
#pragma unroll
      for (int r = 0; r < 32; ++r) {
        float4 x4 = *(const float4*)(&xs[r][k4 << 2]);
        acc[r].x = fmaf(x4.x, w0.x, acc[r].x);
        acc[r].y = fmaf(x4.x, w0.y, acc[r].y);
        acc[r].x = fmaf(x4.y, w1.x, acc[r].x);
        acc[r].y = fmaf(x4.y, w1.y, acc[r].y);
        acc[r].x = fmaf(x4.z, w2.x, acc[r].x);
        acc[r].y = fmaf(x4.z, w2.y, acc[r].y);
        acc[r].x = fmaf(x4.w, w3.x, acc[r].x);
        acc[r].y = fmaf(x4.w, w3.y, acc[r].y);
      }
      w0 = p0; w1 = p1; w2 = p2; w3 = p3;
    }
    const float2 bb = *(const float2*)(b + v);
#pragma unroll
    for (int r = 0; r < 32; ++r) {
      float e = __expf(acc[r].x + bb.x) + __expf(acc[r].y + bb.y);
#pragma unroll
      for (int off = 32; off > 0; off >>= 1) e += __shfl_xor(e, off);
      if (lane == 0) redb[wave * 32 + r] += e;
    }
  }
  __syncthreads();
  if (threadIdx.x < 32) {
    float s = 0.f;
#pragma unroll
    for (int w = 0; w < 8; ++w) s += redb[w * 32 + threadIdx.x];
    lse[m0 + threadIdx.x] = __logf(s);
  }
}

__global__ void k_finish(const float* __restrict__ nll, float* __restrict__ out) {
  const int l = threadIdx.x;
  float v = (l < 16) ? nll[l] : 0.f;
#pragma unroll
  for (int off = 8; off > 0; off >>= 1) v += __shfl_down(v, off);
  if (l == 0) out[0] = v * 0.0625f;
}

// ---------------------------------------------------------------------------
extern "C" void kernel_launch(void* const* d_in, const int* in_sizes, int n_in,
                              void* d_out, int out_size, void* d_ws, size_t ws_size,
                              hipStream_t stream) {
  const float* X        = (const float*)d_in[0];   // (16,512,512)
  const float* W        = (const float*)d_in[1];   // (512,4096)
  const float* b        = (const float*)d_in[2];   // (4096)
  const int*   in_lens  = (const int*)d_in[3];     // (16)
  const int*   labels   = (const int*)d_in[4];     // (16,128)
  const int*   lab_lens = (const int*)d_in[5];     // (16)
  float* out = (float*)d_out;
  char* wsb = (char*)d_ws;

  const size_t NEED = 34906240;
  if (ws_size >= NEED) {
    float* pg  = (float*)(wsb + 32768);      // 8192*32 f
    float* Wgt = (float*)(wsb + 1081344);    // 16*512*132 f
    float* gb  = (float*)(wsb + 5406720);    // 16*129 f
    float* g   = (float*)(wsb + 5414976);    // 16*512*132 f
    unsigned short* Xbf = (unsigned short*)(wsb + 9740416);   // 8 MB
    unsigned short* Wt  = (unsigned short*)(wsb + 18129024);  // 4 MB
    float* af = (float*)(wsb + 26517632);                     // 16*320 f
    float* ab = (float*)(wsb + 26517632 + 20480);

    k_prep1<<<dim3(6656), dim3(256), 0, stream>>>(X, Xbf, W, b, labels, Wgt, gb, Wt);
    k_glp8<<<dim3(1024), dim3(256), 0, stream>>>(X, Wgt, gb, in_lens, g);
    k_main<<<dim3(2080), dim3(256), 0, stream>>>(g, labels, in_lens, lab_lens,
                                                 af, ab, Xbf, Wt, b, pg);
    k_tail2<<<dim3(1), dim3(256), 0, stream>>>(pg, in_lens, af, ab, out);
  } else {
    float* ws    = (float*)d_ws;
    float* lse   = ws;
    float* red_g = ws + 8192;
    float* Wgt   = ws + 8192 + 65536;
    float* gb    = Wgt + 1081344;
    float* g     = gb + 2064;
    float* nll   = g + 1081344;
    k_lse<<<dim3(256), dim3(512), 0, stream>>>(X, W, b, in_lens, lse, red_g);
    k_gather_w<<<dim3(2048), dim3(256), 0, stream>>>(W, b, labels, Wgt, gb);
    k_glp<<<dim3(256), dim3(256), 0, stream>>>(X, Wgt, gb, lse, in_lens, g);
    k_ctc_g<<<dim3(16), dim3(64), 0, stream>>>(g, labels, in_lens, lab_lens, nll);
    k_finish<<<dim3(1), dim3(64), 0, stream>>>(nll, out);
  }
}

// Round 19
// 168.723 us; speedup vs baseline: 1.7473x; 1.1508x over previous
//
#include <hip/hip_runtime.h>

#define NEGF (-1e30f)
#define LOG2E 1.4426950408889634f
#define LN2d  0.6931471805599453

typedef __attribute__((ext_vector_type(8))) short bf16x8;
typedef __attribute__((ext_vector_type(4))) float f32x4;

__device__ __forceinline__ unsigned short f2bf(float x) {
  unsigned u = __float_as_uint(x);
  unsigned r = (u + 0x7FFFu + ((u >> 16) & 1u)) >> 16;
  return (unsigned short)r;
}

// ===========================================================================
// Device bodies
// ===========================================================================

__device__ __forceinline__ void d_cvtx(int bid, int tid,
                                       const float* __restrict__ X,
                                       unsigned short* __restrict__ Xbf) {
  const int i = bid * 256 + tid;
  float4 v = ((const float4*)X)[i];
  ushort4 h;
  h.x = f2bf(v.x); h.y = f2bf(v.y); h.z = f2bf(v.z); h.w = f2bf(v.w);
  ((ushort4*)Xbf)[i] = h;
}

__device__ __forceinline__ void d_gather(int bid, int tid,
                                         const float* __restrict__ W,
                                         const float* __restrict__ b,
                                         const int* __restrict__ labels,
                                         float* __restrict__ Wgt,
                                         float* __restrict__ gb) {
  const int n  = bid >> 7;
  const int kc = bid & 127;
  const int k0 = kc << 2;
  for (int idx = tid; idx < 4 * 129; idx += 256) {
    const int kk = idx / 129;
    const int j  = idx - kk * 129;
    const int c  = (j == 0) ? 0 : labels[n * 128 + (j - 1)];
    const int k  = k0 + kk;
    Wgt[((size_t)(n * 512 + k)) * 132 + j] = W[(size_t)k * 4096 + c];
    if (kc == 0 && kk == 0) gb[n * 129 + j] = b[c];
  }
}

__device__ __forceinline__ void d_wtrans(int bid, int tid, char* smem,
                                         const float* __restrict__ W,
                                         unsigned short* __restrict__ Wt) {
  float (*tile)[65] = (float (*)[65])smem;
  const int kb = bid & 7;
  const int vb = bid >> 3;
  const int k0 = kb << 6, v0 = vb << 6;
#pragma unroll
  for (int it = 0; it < 16; ++it) {
    const int idx = it * 256 + tid;
    const int r = idx >> 6, c = idx & 63;
    tile[r][c] = W[(size_t)(k0 + r) * 4096 + v0 + c];
  }
  __syncthreads();
#pragma unroll
  for (int it = 0; it < 16; ++it) {
    const int idx = it * 256 + tid;
    const int vr = idx >> 6, kc = idx & 63;
    Wt[(size_t)(v0 + vr) * 512 + k0 + kc] = f2bf(tile[kc][vr]);
  }
}

// ---- gemm body (bf16 MFMA, swizzled, validated r12) ----------------------
__device__ __forceinline__ void stage_tile(const unsigned short* __restrict__ src,
                                           int r0, char* ldsbase, int wave,
                                           int tid, int kbyte) {
#pragma unroll
  for (int j = 0; j < 2; ++j) {
    const int chunk = (tid & 3) ^ ((tid >> 3) & 3);
    const char* gp = (const char*)src +
        (size_t)(r0 + j * 64 + (tid >> 2)) * 1024 + kbyte + chunk * 16;
    char* lp = ldsbase + j * 4096 + wave * 1024;
    __builtin_amdgcn_global_load_lds(
        (const __attribute__((address_space(1))) unsigned int*)gp,
        (__attribute__((address_space(3))) unsigned int*)lp, 16, 0, 0);
  }
}

__device__ __forceinline__ void d_gemm(int gid, int tid, char* smem,
                                       const unsigned short* __restrict__ Xbf,
                                       const unsigned short* __restrict__ Wt,
                                       const float* __restrict__ bvec,
                                       const int* __restrict__ lens,
                                       float* __restrict__ pg) {
  const int bm = gid >> 5;
  const int bn = gid & 31;
  const int n  = bm >> 2;
  const int t0 = (bm & 3) << 7;
  if (t0 >= lens[n]) return;
  const int m0 = bm << 7;
  const int v0 = bn << 7;

  const int wave = tid >> 6;
  const int lane = tid & 63;
  const int lrow = lane & 15;
  const int lk   = (lane >> 4) * 16;
  const int lks  = lk ^ (((lrow >> 1) & 3) << 4);
  const int wr   = wave >> 1;
  const int wn   = wave & 1;

  f32x4 acc[4][4];
#pragma unroll
  for (int mi = 0; mi < 4; ++mi)
#pragma unroll
    for (int ni = 0; ni < 4; ++ni) acc[mi][ni] = (f32x4){0.f, 0.f, 0.f, 0.f};

  {
    char* buf = smem;
    stage_tile(Xbf, m0, buf + 0,    wave, tid, 0);
    stage_tile(Wt,  v0, buf + 8192, wave, tid, 0);
  }
  __syncthreads();

  int cur = 0;
  for (int kk = 0; kk < 16; ++kk) {
    if (kk < 15) {
      char* nbuf = smem + (cur ^ 1) * 16384;
      const int kb = (kk + 1) << 6;
      stage_tile(Xbf, m0, nbuf + 0,    wave, tid, kb);
      stage_tile(Wt,  v0, nbuf + 8192, wave, tid, kb);
    }
    const char* buf = smem + cur * 16384;
    bf16x8 ah[4], bh[4];
#pragma unroll
    for (int mi = 0; mi < 4; ++mi) {
      const int off = (wr * 64 + mi * 16 + lrow) * 64 + lks;
      ah[mi] = *(const bf16x8*)(buf + off);
    }
#pragma unroll
    for (int ni = 0; ni < 4; ++ni) {
      const int off = (wn * 64 + ni * 16 + lrow) * 64 + lks;
      bh[ni] = *(const bf16x8*)(buf + 8192 + off);
    }
#pragma unroll
    for (int mi = 0; mi < 4; ++mi)
#pragma unroll
      for (int ni = 0; ni < 4; ++ni)
        acc[mi][ni] = __builtin_amdgcn_mfma_f32_16x16x32_bf16(ah[mi], bh[ni], acc[mi][ni], 0, 0, 0);
    __syncthreads();
    cur ^= 1;
  }

  const float lg2e = LOG2E;
  float bias[4];
#pragma unroll
  for (int ni = 0; ni < 4; ++ni) bias[ni] = bvec[v0 + wn * 64 + ni * 16 + lrow];
  float* part = (float*)(smem + 32768);
#pragma unroll
  for (int mi = 0; mi < 4; ++mi)
#pragma unroll
    for (int reg = 0; reg < 4; ++reg) {
      float s = 0.f;
#pragma unroll
      for (int ni = 0; ni < 4; ++ni)
        s += exp2f((acc[mi][ni][reg] + bias[ni]) * lg2e);
#pragma unroll
      for (int msk = 1; msk < 16; msk <<= 1) s += __shfl_xor(s, msk);
      if (lrow == 0)
        part[(wr * 64 + mi * 16 + (lane >> 4) * 4 + reg) * 2 + wn] = s;
    }
  __syncthreads();
  if (tid < 128)
    pg[(size_t)(m0 + tid) * 32 + bn] = part[tid * 2 + 0] + part[tid * 2 + 1];
}

// ---- CTC scan body (fwd/bwd split, LOG2 domain, validated r15/r16) -------
__device__ __forceinline__ float lae32(float x, float y, float z) {
  float m = fmaxf(fmaxf(x, y), z);
  float e = exp2f(x - m) + exp2f(y - m) + exp2f(z - m);
  return m + __log2f(e);
}

__device__ __forceinline__ float lae3n(float x, float y, float z) {
  float m = fmaxf(fmaxf(x, y), z);
  float e = __expf(x - m) + __expf(y - m) + __expf(z - m);
  return m + __logf(e);
}

__device__ __forceinline__ void stage32(const float* __restrict__ gsrc,
                                        char* ldsbase, int tid, int wave) {
#pragma unroll
  for (int k = 0; k < 4; ++k) {
    const char* gp = (const char*)gsrc + k * 4096 + (size_t)tid * 16;
    char* lp = ldsbase + k * 4096 + wave * 1024;
    __builtin_amdgcn_global_load_lds(
        (const __attribute__((address_space(1))) unsigned int*)gp,
        (__attribute__((address_space(3))) unsigned int*)lp, 16, 0, 0);
  }
  if (tid < 32) {
    const char* gp = (const char*)gsrc + 16384 + (size_t)tid * 16;
    char* lp = ldsbase + 16384;
    __builtin_amdgcn_global_load_lds(
        (const __attribute__((address_space(1))) unsigned int*)gp,
        (__attribute__((address_space(3))) unsigned int*)lp, 16, 0, 0);
  }
}

__device__ void d_scan(int sbid, int tid, char* smem,
                       const float* __restrict__ g,
                       const int* __restrict__ labels,
                       const int* __restrict__ in_lens,
                       const int* __restrict__ lab_lens,
                       float* __restrict__ af,
                       float* __restrict__ ab) {
  const int n    = sbid >> 1;
  const int dir  = sbid & 1;
  const int wave = tid >> 6;
  const int l    = tid & 63;
  const int len  = in_lens[n];
  const int tm   = len >> 1;
  const float* gn = g + (size_t)n * 512 * 132;
  const int s0 = 5 * l;

  int jm0, jm1, jm2, jm3, jm4;
  {
    int jmv[5];
#pragma unroll
    for (int i = 0; i < 5; ++i) {
      const int s = s0 + i;
      jmv[i] = (s < 257 && (s & 1)) ? ((s + 1) >> 1) : 0;
    }
    jm0 = jmv[0]; jm1 = jmv[1]; jm2 = jmv[2]; jm3 = jmv[3]; jm4 = jmv[4];
  }

  if (dir == 0) {
    bool sk0, sk1, sk2, sk3, sk4;
    {
      bool skv[5];
#pragma unroll
      for (int i = 0; i < 5; ++i) {
        const int s = s0 + i;
        skv[i] = false;
        if (s < 257 && (s & 1) && s >= 3) {
          const int li = (s - 1) >> 1;
          const int cl = labels[n * 128 + li];
          skv[i] = (cl != 0) && (cl != labels[n * 128 + li - 1]);
        }
      }
      sk0 = skv[0]; sk1 = skv[1]; sk2 = skv[2]; sk3 = skv[3]; sk4 = skv[4];
    }
    stage32(gn, smem, tid, wave);
    __syncthreads();

    float a0 = NEGF, a1 = NEGF, a2 = NEGF, a3 = NEGF, a4 = NEGF;
    if (tid < 64 && l == 0) {
      const float* B0 = (const float*)smem;
      a0 = B0[0]; a1 = B0[1];
    }
    float a3p = NEGF, a4p = NEGF;

    int t = 1, c = 0;
    while (true) {
      const bool more = ((c + 1) << 5) <= tm;
      if (more)
        stage32(gn + (size_t)((c + 1) << 5) * 132,
                smem + ((c + 1) & 1) * 16896, tid, wave);
      if (tid < 64) {
        const float* B = (const float*)(smem + (c & 1) * 16896);
        const int ce = (c << 5) + 31;
        const int tend = (tm < ce) ? tm : ce;
        int ro = (t - (c << 5)) * 132;
        float p0 = B[ro + jm0], p1 = B[ro + jm1], p2 = B[ro + jm2],
              p3 = B[ro + jm3], p4 = B[ro + jm4];
        for (; t <= tend; ++t) {
          const int ro2 = (t < tend) ? ro + 132 : ro;
          const float q0 = B[ro2 + jm0];
          const float q1 = B[ro2 + jm1];
          const float q2 = B[ro2 + jm2];
          const float q3 = B[ro2 + jm3];
          const float q4 = B[ro2 + jm4];
          float x3 = a3p, x4 = a4p;
          if (l == 0) { x3 = NEGF; x4 = NEGF; }
          const float n3 = lae32(a3, a2, sk3 ? a1 : NEGF) + p3;
          const float n4 = lae32(a4, a3, sk4 ? a2 : NEGF) + p4;
          a3p = __shfl_up(n3, 1);
          a4p = __shfl_up(n4, 1);
          const float n0 = lae32(a0, x4, sk0 ? x3 : NEGF) + p0;
          const float n1 = lae32(a1, a0, sk1 ? x4 : NEGF) + p1;
          const float n2 = lae32(a2, a1, sk2 ? a0 : NEGF) + p2;
          a0 = n0; a1 = n1; a2 = n2; a3 = n3; a4 = n4;
          p0 = q0; p1 = q1; p2 = q2; p3 = q3; p4 = q4;
          ro = ro2;
        }
      }
      if (!more) break;
      __syncthreads();
      ++c;
    }
    if (tid < 64) {
      float* o = af + n * 320 + s0;
      o[0] = a0; o[1] = a1; o[2] = a2; o[3] = a3; o[4] = a4;
    }
  } else {
    bool skd0, skd1, skd2, skd3, skd4;
    {
      bool skv[5];
#pragma unroll
      for (int i = 0; i < 5; ++i) {
        const int s2 = s0 + i + 2;
        skv[i] = false;
        if (s2 < 257 && (s2 & 1) && s2 >= 3) {
          const int li = (s2 - 1) >> 1;
          const int cl = labels[n * 128 + li];
          skv[i] = (cl != 0) && (cl != labels[n * 128 + li - 1]);
        }
      }
      skd0 = skv[0]; skd1 = skv[1]; skd2 = skv[2]; skd3 = skv[3]; skd4 = skv[4];
    }
    int c = (len - 1) >> 5;
    stage32(gn + (size_t)(c << 5) * 132, smem + (c & 1) * 16896, tid, wave);
    __syncthreads();

    float b0, b1, b2, b3, b4;
    {
      const int ll = lab_lens[n];
      const int i1 = 2 * ll, i2 = 2 * ll - 1;
      b0 = (s0 + 0 == i1 || s0 + 0 == i2) ? 0.f : NEGF;
      b1 = (s0 + 1 == i1 || s0 + 1 == i2) ? 0.f : NEGF;
      b2 = (s0 + 2 == i1 || s0 + 2 == i2) ? 0.f : NEGF;
      b3 = (s0 + 3 == i1 || s0 + 3 == i2) ? 0.f : NEGF;
      b4 = (s0 + 4 == i1 || s0 + 4 == i2) ? 0.f : NEGF;
    }

    int t = len - 2;
    while (true) {
      const bool more = (c << 5) > tm + 1;
      if (more)
        stage32(gn + (size_t)((c - 1) << 5) * 132,
                smem + ((c - 1) & 1) * 16896, tid, wave);
      if (tid < 64) {
        const float* B = (const float*)(smem + (c & 1) * 16896);
        const int cl0 = (c << 5) - 1;
        const int tlo = (tm > cl0) ? tm : cl0;
        int ro = (t + 1 - (c << 5)) * 132;
        float p0 = B[ro + jm0], p1 = B[ro + jm1], p2 = B[ro + jm2],
              p3 = B[ro + jm3], p4 = B[ro + jm4];
        for (; t >= tlo; --t) {
          const int ro2 = (t - 1 >= tlo) ? ro - 132 : ro;
          const float q0 = B[ro2 + jm0];
          const float q1 = B[ro2 + jm1];
          const float q2 = B[ro2 + jm2];
          const float q3 = B[ro2 + jm3];
          const float q4 = B[ro2 + jm4];
          const float c0 = b0 + p0;
          const float c1 = b1 + p1;
          float c5 = __shfl_down(c0, 1);
          float c6 = __shfl_down(c1, 1);
          const float c2 = b2 + p2;
          const float c3 = b3 + p3;
          const float c4 = b4 + p4;
          const float m0n = lae32(c0, c1, skd0 ? c2 : NEGF);
          const float m1n = lae32(c1, c2, skd1 ? c3 : NEGF);
          const float m2n = lae32(c2, c3, skd2 ? c4 : NEGF);
          if (l == 63) { c5 = NEGF; c6 = NEGF; }
          const float m3n = lae32(c3, c4, skd3 ? c5 : NEGF);
          const float m4n = lae32(c4, c5, skd4 ? c6 : NEGF);
          b0 = m0n; b1 = m1n; b2 = m2n; b3 = m3n; b4 = m4n;
          p0 = q0; p1 = q1; p2 = q2; p3 = q3; p4 = q4;
          ro = ro2;
        }
      }
      if (!more) break;
      __syncthreads();
      --c;
    }
    if (tid < 64) {
      float* o = ab + n * 320 + s0;
      o[0] = b0; o[1] = b1; o[2] = b2; o[3] = b3; o[4] = b4;
    }
  }
}

// ===========================================================================
// Launchers (main path) — round-16 champion configuration
// ===========================================================================

// prep1: [0,4096) cvtx ; [4096,6144) gather ; [6144,6656) wtrans
__global__ __launch_bounds__(256) void k_prep1(const float* __restrict__ X,
                                               unsigned short* __restrict__ Xbf,
                                               const float* __restrict__ W,
                                               const float* __restrict__ b,
                                               const int* __restrict__ labels,
                                               float* __restrict__ Wgt,
                                               float* __restrict__ gb,
                                               unsigned short* __restrict__ Wt) {
  __shared__ __align__(16) char smem[16640];
  const int bid = blockIdx.x;
  if (bid < 4096)      d_cvtx(bid, threadIdx.x, X, Xbf);
  else if (bid < 6144) d_gather(bid - 4096, threadIdx.x, W, b, labels, Wgt, gb);
  else                 d_wtrans(bid - 6144, threadIdx.x, smem, W, Wt);
}

// glp8: 8 rows/block (1024 blocks, all co-resident) — log2-domain raw logits.
__global__ __launch_bounds__(256) void k_glp8(const float* __restrict__ X,
                                              const float* __restrict__ Wgt,
                                              const float* __restrict__ gb,
                                              const int* __restrict__ lens,
                                              float* __restrict__ g) {
  __shared__ float xs[8][512];   // 16 KB
  const int bid = blockIdx.x;
  const int n  = bid >> 6;
  const int r0 = (bid & 63) << 3;
  if (r0 >= lens[n]) return;
  const int m0 = n * 512 + r0;
  {
    const float4* Xv = (const float4*)(X + (size_t)m0 * 512);
    float4* xsv = (float4*)(&xs[0][0]);
    for (int i = threadIdx.x; i < 8 * 128; i += 256) xsv[i] = Xv[i];
  }
  __syncthreads();
  const int j = threadIdx.x;
  if (j >= 129) return;
  const float* wp = Wgt + (size_t)(n * 512) * 132 + j;
  float acc[8];
#pragma unroll
  for (int r = 0; r < 8; ++r) acc[r] = 0.f;
  float w0 = wp[0], w1 = wp[132], w2 = wp[264], w3 = wp[396];
  for (int k4 = 0; k4 < 128; ++k4) {
    const int kn = (k4 + 1) & 127;
    float p0 = wp[(size_t)(kn * 4 + 0) * 132];
    float p1 = wp[(size_t)(kn * 4 + 1) * 132];
    float p2 = wp[(size_t)(kn * 4 + 2) * 132];
    float p3 = wp[(size_t)(kn * 4 + 3) * 132];
#pragma unroll
    for (int r = 0; r < 8; ++r) {
      float4 x4 = *(const float4*)(&xs[r][k4 << 2]);
      acc[r] = fmaf(x4.x, w0, acc[r]);
      acc[r] = fmaf(x4.y, w1, acc[r]);
      acc[r] = fmaf(x4.z, w2, acc[r]);
      acc[r] = fmaf(x4.w, w3, acc[r]);
    }
    w0 = p0; w1 = p1; w2 = p2; w3 = p3;
  }
  const float bb = gb[n * 129 + j];
#pragma unroll
  for (int r = 0; r < 8; ++r)
    g[(size_t)(m0 + r) * 132 + j] = (acc[r] + bb) * LOG2E;
}

// main: blocks [0,32) CTC scan ; [32,2080) gemm
__global__ __launch_bounds__(256, 4) void k_main(const float* __restrict__ g,
                                                 const int* __restrict__ labels,
                                                 const int* __restrict__ in_lens,
                                                 const int* __restrict__ lab_lens,
                                                 float* __restrict__ af,
                                                 float* __restrict__ ab,
                                                 const unsigned short* __restrict__ Xbf,
                                                 const unsigned short* __restrict__ Wt,
                                                 const float* __restrict__ bvec,
                                                 float* __restrict__ pg) {
  __shared__ __align__(16) char smem[33792];
  const int bid = blockIdx.x;
  if (bid < 32) {
    d_scan(bid, threadIdx.x, smem, g, labels, in_lens, lab_lens, af, ab);
  } else {
    d_gemm(bid - 32, threadIdx.x, smem, Xbf, Wt, bvec, in_lens, pg);
  }
}

// tail: 16 blocks — Sn (nats, double tree) + comb -> nll
__global__ __launch_bounds__(256) void k_tail(const float* __restrict__ pg,
                                              const int* __restrict__ lens,
                                              const float* __restrict__ af,
                                              const float* __restrict__ ab,
                                              float* __restrict__ nll) {
  const int n = blockIdx.x, tid = threadIdx.x;
  const int len = lens[n];
  __shared__ double red[256];
  double s = 0.0;
  for (int t = tid; t < len; t += 256) {
    const float4* p = (const float4*)(pg + ((size_t)(n * 512 + t)) * 32);
    float e = 0.f;
#pragma unroll
    for (int i = 0; i < 8; ++i) { float4 v = p[i]; e += v.x + v.y + v.z + v.w; }
    s += (double)__logf(e);
  }
  red[tid] = s;
  __syncthreads();
  for (int off = 128; off > 0; off >>= 1) {
    if (tid < off) red[tid] += red[tid + off];
    __syncthreads();
  }
  if (tid < 64) {
    const int l = tid;
    const int s0 = 5 * l;
    float v0 = NEGF, v1 = NEGF, v2 = NEGF, v3 = NEGF, v4 = NEGF;
    const float* f = af + n * 320 + s0;
    const float* bb = ab + n * 320 + s0;
    if (s0 + 0 < 257) v0 = f[0] + bb[0];
    if (s0 + 1 < 257) v1 = f[1] + bb[1];
    if (s0 + 2 < 257) v2 = f[2] + bb[2];
    if (s0 + 3 < 257) v3 = f[3] + bb[3];
    if (s0 + 4 < 257) v4 = f[4] + bb[4];
    float M = fmaxf(fmaxf(v0, v1), fmaxf(fmaxf(v2, v3), v4));
#pragma unroll
    for (int off = 1; off < 64; off <<= 1) M = fmaxf(M, __shfl_xor(M, off));
    float e = exp2f(v0 - M) + exp2f(v1 - M) + exp2f(v2 - M)
            + exp2f(v3 - M) + exp2f(v4 - M);
#pragma unroll
    for (int off = 1; off < 64; off <<= 1) e += __shfl_xor(e, off);
    if (l == 0)
      nll[n] = (float)(red[0] - (double)(M + __log2f(e)) * LN2d);
  }
}

__global__ void k_finish(const float* __restrict__ nll, float* __restrict__ out) {
  const int l = threadIdx.x;
  float v = (l < 16) ? nll[l] : 0.f;
#pragma unroll
  for (int off = 8; off > 0; off >>= 1) v += __shfl_down(v, off);
  if (l == 0) out[0] = v * 0.0625f;
}

// ===========================================================================
// Fallback path (round-3 structure, validated, nats domain).
// ===========================================================================
__global__ void k_gather_w(const float* __restrict__ W,
                           const float* __restrict__ b,
                           const int* __restrict__ labels,
                           float* __restrict__ Wgt,
                           float* __restrict__ gb) {
  d_gather(blockIdx.x, threadIdx.x, W, b, labels, Wgt, gb);
}

__global__ __launch_bounds__(256) void k_glp(const float* __restrict__ X,
                                             const float* __restrict__ Wgt,
                                             const float* __restrict__ gb,
                                             const float* __restrict__ lse,
                                             const int* __restrict__ lens,
                                             float* __restrict__ g) {
  const int blk = blockIdx.x;
  const int n   = blk >> 4;
  const int t0  = (blk & 15) << 5;
  if (t0 >= lens[n]) return;
  const int m0 = n * 512 + t0;
  __shared__ float xs[32][512];
  {
    const float4* Xv = (const float4*)(X + (size_t)m0 * 512);
    float4* xsv = (float4*)(&xs[0][0]);
    for (int i = threadIdx.x; i < 32 * 128; i += 256) xsv[i] = Xv[i];
  }
  __syncthreads();
  const int j = threadIdx.x;
  if (j >= 129) return;
  const float* wp = Wgt + (size_t)(n * 512) * 132 + j;
  float acc[32];
#pragma unroll
  for (int r = 0; r < 32; ++r) acc[r] = 0.f;
  float w0 = wp[0], w1 = wp[132], w2 = wp[264], w3 = wp[396];
  for (int k4 = 0; k4 < 128; ++k4) {
    const int kn = (k4 + 1) & 127;
    float p0 = wp[(size_t)(kn * 4 + 0) * 132];
    float p1 = wp[(size_t)(kn * 4 + 1) * 132];
    float p2 = wp[(size_t)(kn * 4 + 2) * 132];
    float p3 = wp[(size_t)(kn * 4 + 3) * 132];
#pragma unroll
    for (int r = 0; r < 32; ++r) {
      float4 x4 = *(const float4*)(&xs[r][k4 << 2]);
      acc[r] = fmaf(x4.x, w0, acc[r]);
      acc[r] = fmaf(x4.y, w1, acc[r]);
      acc[r] = fmaf(x4.z, w2, acc[r]);
      acc[r] = fmaf(x4.w, w3, acc[r]);
    }
    w0 = p0; w1 = p1; w2 = p2; w3 = p3;
  }
  const float bb = gb[n * 129 + j];
#pragma unroll
  for (int r = 0; r < 32; ++r)
    g[(size_t)(m0 + r) * 132 + j] = acc[r] + bb - lse[m0 + r];
}

__global__ void k_ctc_g(const float* __restrict__ g,
                        const int* __restrict__ labels,
                        const int* __restrict__ in_lens,
                        const int* __restrict__ lab_lens,
                        float* __restrict__ nll) {
  const int n = blockIdx.x;
  const int l = threadIdx.x;
  const float* gn = g + (size_t)n * 512 * 132;
  const int len = in_lens[n];
  const int s0 = 5 * l;
  int jm[5]; bool sk[5];
#pragma unroll
  for (int i = 0; i < 5; ++i) {
    const int s = s0 + i;
    const bool valid = (s < 257);
    jm[i] = (valid && (s & 1)) ? ((s + 1) >> 1) : 0;
    sk[i] = false;
    if (valid && (s & 1) && s >= 3) {
      const int li = (s - 1) >> 1;
      const int cl = labels[n * 128 + li];
      sk[i] = (cl != 0) && (cl != labels[n * 128 + li - 1]);
    }
  }
  float a[5];
  a[0] = (l == 0) ? gn[0] : NEGF;
  a[1] = (l == 0) ? gn[1] : NEGF;
  a[2] = NEGF; a[3] = NEGF; a[4] = NEGF;
  float lp[5];
#pragma unroll
  for (int i = 0; i < 5; ++i) lp[i] = gn[132 + jm[i]];
  for (int t = 1; t < len; ++t) {
    const int tp = (t + 1 < len) ? (t + 1) : t;
    float np[5];
#pragma unroll
    for (int i = 0; i < 5; ++i) np[i] = gn[(size_t)tp * 132 + jm[i]];
    float a3p = __shfl_up(a[3], 1);
    float a4p = __shfl_up(a[4], 1);
    if (l == 0) { a3p = NEGF; a4p = NEGF; }
    const float b0 = lae3n(a[0], a4p,  sk[0] ? a3p  : NEGF) + lp[0];
    const float b1 = lae3n(a[1], a[0], sk[1] ? a4p  : NEGF) + lp[1];
    const float b2 = lae3n(a[2], a[1], sk[2] ? a[0] : NEGF) + lp[2];
    const float b3 = lae3n(a[3], a[2], sk[3] ? a[1] : NEGF) + lp[3];
    const float b4 = lae3n(a[4], a[3], sk[4] ? a[2] : NEGF) + lp[4];
    a[0] = b0; a[1] = b1; a[2] = b2; a[3] = b3; a[4] = b4;
#pragma unroll
    for (int i = 0; i < 5; ++i) lp[i] = np[i];
  }
  __shared__ float al[320];
#pragma unroll
  for (int i = 0; i < 5; ++i) al[s0 + i] = a[i];
  __syncthreads();
  if (l == 0) {
    const int ll  = lab_lens[n];
    const int idx = 2 * ll;
    const float e1 = al[idx], e2 = al[idx - 1];
    const float m = fmaxf(e1, e2);
    const float r = m + __logf(__expf(e1 - m) + __expf(e2 - m));
    nll[n] = -r;
  }
}

__global__ __launch_bounds__(512, 2) void k_lse(const float* __restrict__ X,
                                                const float* __restrict__ W,
                                                const float* __restrict__ b,
                                                const int* __restrict__ lens,
                                                float* __restrict__ lse,
                                                float* __restrict__ red_g) {
  const int blk = blockIdx.x;
  const int n   = blk >> 4;
  const int t0  = (blk & 15) << 5;
  if (t0 >= lens[n]) return;
  const int m0 = n * 512 + t0;
  __shared__ float xs[32][512];
  {
    const float4* Xv = (const float4*)(X + (size_t)m0 * 512);
    float4* xsv = (float4*)(&xs[0][0]);
    for (int i = threadIdx.x; i < 32 * 128; i += 512) xsv[i] = Xv[i];
  }
  float* redb = red_g + (size_t)blk * 256;
  for (int i = threadIdx.x; i < 256; i += 512) redb[i] = 0.f;
  __syncthreads();
  const int wave = threadIdx.x >> 6;
  const int lane = threadIdx.x & 63;
  for (int j = 0; j < 4; ++j) {
    const int v = (j << 10) + (threadIdx.x << 1);
    const float* Wv = W + v;
    float2 acc[32];
#pragma unroll
    for (int r = 0; r < 32; ++r) acc[r] = make_float2(0.f, 0.f);
    float2 w0 = *(const float2*)(Wv + 0 * 4096);
    float2 w1 = *(const float2*)(Wv + 1 * 4096);
    float2 w2 = *(const float2*)(Wv + 2 * 4096);
    float2 w3 = *(const float2*)(Wv + 3 * 4096);
    for (int k4 = 0; k4 < 128; ++k4) {
      const int kn = (k4 + 1) & 127;
      float2 p0 = *(const float2*)(Wv + (kn * 4 + 0) * 4096);
      float2 p1 = *(const float2*)(Wv + (kn * 4 + 1) * 4096);
      float2 p2 = *(const float2*)(Wv + (kn * 4 + 2) * 4096);
      float2 p3 = *(const float2*)(Wv + (kn * 4 + 3) * 4096);
#pragma unroll
      for (int r = 0; r < 32; ++r) {
        float4 x4 = *(const float4*)(&xs[r][k4 << 2]);
        acc[r].x = fmaf(x4.x, w0.x, acc[r].x);
        acc[r].y = fmaf(x4.x, w0.y, acc[r].y);
        acc[r].x = fmaf(x4.y, w1.x, acc[r].x);
        acc[r].y = fmaf(x4.y, w1.y, acc[r].y);
        acc[r].x = fmaf(x4.z, w2.x, acc[r].x);
        acc[r].y = fmaf(x4.z, w2.y, acc[r].y);
        acc[r].x = fmaf(x4.w, w3.x, acc[r].x);
        acc[r].y = fmaf(x4.w, w3.y, acc[r].y);
      }
      w0 = p0; w1 = p1; w2 = p2; w3 = p3;
    }
    const float2 bb = *(const float2*)(b + v);
#pragma unroll
    for (int r = 0; r < 32; ++r) {
      float e = __expf(acc[r].x + bb.x) + __expf(acc[r].y + bb.y);
#pragma unroll
      for (int off = 32; off > 0; off >>= 1) e += __shfl_xor(e, off);
      if (lane == 0) redb[wave * 32 + r] += e;
    }
  }
  __syncthreads();
  if (threadIdx.x < 32) {
    float s = 0.f;
#pragma unroll
    for (int w = 0; w < 8; ++w) s += redb[w * 32 + threadIdx.x];
    lse[m0 + threadIdx.x] = __logf(s);
  }
}

// ---------------------------------------------------------------------------
extern "C" void kernel_launch(void* const* d_in, const int* in_sizes, int n_in,
                              void* d_out, int out_size, void* d_ws, size_t ws_size,
                              hipStream_t stream) {
  const float* X        = (const float*)d_in[0];   // (16,512,512)
  const float* W        = (const float*)d_in[1];   // (512,4096)
  const float* b        = (const float*)d_in[2];   // (4096)
  const int*   in_lens  = (const int*)d_in[3];     // (16)
  const int*   labels   = (const int*)d_in[4];     // (16,128)
  const int*   lab_lens = (const int*)d_in[5];     // (16)
  float* out = (float*)d_out;
  char* wsb = (char*)d_ws;

  const size_t NEED = 34906240;
  if (ws_size >= NEED) {
    float* pg  = (float*)(wsb + 32768);      // 8192*32 f
    float* Wgt = (float*)(wsb + 1081344);    // 16*512*132 f
    float* gb  = (float*)(wsb + 5406720);    // 16*129 f
    float* g   = (float*)(wsb + 5414976);    // 16*512*132 f
    float* nll = (float*)(wsb + 9740352);    // 16 f
    unsigned short* Xbf = (unsigned short*)(wsb + 9740416);   // 8 MB
    unsigned short* Wt  = (unsigned short*)(wsb + 18129024);  // 4 MB
    float* af = (float*)(wsb + 26517632);                     // 16*320 f
    float* ab = (float*)(wsb + 26517632 + 20480);

    k_prep1<<<dim3(6656), dim3(256), 0, stream>>>(X, Xbf, W, b, labels, Wgt, gb, Wt);
    k_glp8<<<dim3(1024), dim3(256), 0, stream>>>(X, Wgt, gb, in_lens, g);
    k_main<<<dim3(2080), dim3(256), 0, stream>>>(g, labels, in_lens, lab_lens,
                                                 af, ab, Xbf, Wt, b, pg);
    k_tail<<<dim3(16), dim3(256), 0, stream>>>(pg, in_lens, af, ab, nll);
    k_finish<<<dim3(1), dim3(64), 0, stream>>>(nll, out);
  } else {
    float* ws    = (float*)d_ws;
    float* lse   = ws;
    float* red_g = ws + 8192;
    float* Wgt   = ws + 8192 + 65536;
    float* gb    = Wgt + 1081344;
    float* g     = gb + 2064;
    float* nll   = g + 1081344;
    k_lse<<<dim3(256), dim3(512), 0, stream>>>(X, W, b, in_lens, lse, red_g);
    k_gather_w<<<dim3(2048), dim3(256), 0, stream>>>(W, b, labels, Wgt, gb);
    k_glp<<<dim3(256), dim3(256), 0, stream>>>(X, Wgt, gb, lse, in_lens, g);
    k_ctc_g<<<dim3(16), dim3(64), 0, stream>>>(g, labels, in_lens, lab_lens, nll);
    k_finish<<<dim3(1), dim3(64), 0, stream>>>(nll, out);
  }
}